// Round 8
// baseline (2229.679 us; speedup 1.0000x reference)
//
#include <hip/hip_runtime.h>
#include <math.h>

#define NN 50000
#define FIN 300
#define SS 304   // fp16 shadow row stride (halves)
constexpr float ALPHA_C = 0.5f;
constexpr float BETA_C  = 0.09531017980432486f;  // log(1.1)
constexpr float NEG_SLOPE = 0.2f;

typedef unsigned short u16;
typedef __attribute__((ext_vector_type(8))) short short8;
typedef __attribute__((ext_vector_type(4))) float f32x4;
typedef _Float16 hf4 __attribute__((ext_vector_type(4)));

// ---------------- CSR build ----------------
__global__ void hist_kernel(const int* __restrict__ dst, int* __restrict__ deg, int E) {
    int e = blockIdx.x * blockDim.x + threadIdx.x;
    if (e < E) atomicAdd(&deg[dst[e]], 1);
}

__global__ void scan_kernel(const int* __restrict__ deg, int* __restrict__ rowptr, int n) {
    __shared__ int sh[1024];
    __shared__ int carry;
    if (threadIdx.x == 0) { carry = 0; rowptr[0] = 0; }
    __syncthreads();
    for (int base = 0; base < n; base += 1024) {
        int i = base + threadIdx.x;
        int v = (i < n) ? deg[i] : 0;
        sh[threadIdx.x] = v;
        __syncthreads();
        for (int off = 1; off < 1024; off <<= 1) {
            int t = (threadIdx.x >= off) ? sh[threadIdx.x - off] : 0;
            __syncthreads();
            sh[threadIdx.x] += t;
            __syncthreads();
        }
        if (i < n) rowptr[i + 1] = sh[threadIdx.x] + carry;
        __syncthreads();
        if (threadIdx.x == 0) carry += sh[1023];
        __syncthreads();
    }
}

__global__ void dinv_kernel(const int* __restrict__ deg, float* __restrict__ dinv, int n) {
    int i = blockIdx.x * blockDim.x + threadIdx.x;
    if (i < n) dinv[i] = rsqrtf((float)deg[i] + 1.0f);
}

__global__ void copy_int_kernel(const int* __restrict__ a, int* __restrict__ b, int n) {
    int i = blockIdx.x * blockDim.x + threadIdx.x;
    if (i < n) b[i] = a[i];
}

__global__ void fill_kernel(const int* __restrict__ src, const int* __restrict__ dst,
                            const float* __restrict__ dinv, int* __restrict__ cursor,
                            int* __restrict__ csr_src, float* __restrict__ csr_w, int E) {
    int e = blockIdx.x * blockDim.x + threadIdx.x;
    if (e < E) {
        int s = src[e], d = dst[e];
        int p = atomicAdd(&cursor[d], 1);
        csr_src[p] = s;
        csr_w[p]   = dinv[s] * dinv[d];
    }
}

// ---------------- weight split: W[k][c] -> WhT/WlT [c][k] bf16, zero-padded ----------------
__global__ void splitw_kernel(const float* __restrict__ W, u16* __restrict__ WhT,
                              u16* __restrict__ WlT, int K, int M, int Kp, int total) {
    int t = blockIdx.x * blockDim.x + threadIdx.x;
    if (t >= total) return;
    int c = t / Kp, k = t - c * Kp;
    float x = (c < M && k < K) ? W[(size_t)k * M + c] : 0.f;
    unsigned u = __float_as_uint(x);
    WhT[t] = (u16)(u >> 16);
    float lo = x - __uint_as_float(u & 0xFFFF0000u);
    WlT[t] = (u16)(__float_as_uint(lo) >> 16);
}

// ---------------- all-M MFMA GEMM: block = 64 rows x Mp cols; A read once ----------------
// C = cAB*(A@W) + cA*A + bias; optional fp16 shadow. W pre-split/transposed bf16 [Mp][Kp].
// MT = Mp/16 (compile-time). 4 waves x 16-row slabs. Markidis 3-term.
template<int MT>
__global__ __launch_bounds__(256)
void gemm_allm_kernel(const float* __restrict__ A, const u16* __restrict__ WhT,
                      const u16* __restrict__ WlT, float* __restrict__ C,
                      _Float16* __restrict__ Cs, int n, int K, int M, int Kp,
                      float cAB, float cA, const float* __restrict__ bias) {
    __shared__ u16 sAh[64 * 40], sAl[64 * 40];
    __shared__ u16 sWh[MT * 16 * 40], sWl[MT * 16 * 40];
    const int tid = threadIdx.x;
    const int rowBase = blockIdx.x * 64;
    const int lane = tid & 63, wid = tid >> 6;
    const int wr = wid * 16;                  // wave's 16-row slab
    const int fr = lane & 15, ko = (lane >> 4) * 8;

    f32x4 acc[MT] = {};

    for (int k0 = 0; k0 < Kp; k0 += 32) {
        // stage W tile [Mp][32] from arena (L2-hot; zero-padded, no guards)
#pragma unroll
        for (int it = 0; it < MT; ++it) {     // MT*64 quads / 256 threads
            int idx = it * 256 + tid;
            int c = idx >> 2, kq = (idx & 3) * 8;
            size_t g = (size_t)c * Kp + k0 + kq;
            *(uint4*)&sWh[c * 40 + kq] = *(const uint4*)&WhT[g];
            *(uint4*)&sWl[c * 40 + kq] = *(const uint4*)&WlT[g];
        }
        // stage A tile [64][32]: fp32 -> split bf16 hi/lo
        const bool fullk = (k0 + 32 <= K);
#pragma unroll
        for (int it = 0; it < 2; ++it) {
            int idx = it * 256 + tid;
            int r = idx >> 3, kb = (idx & 7) * 4;
            int gr = rowBase + r, kk = k0 + kb;
            float x0 = 0.f, x1 = 0.f, x2 = 0.f, x3 = 0.f;
            if (gr < n) {
                const float* ap = A + (size_t)gr * K + kk;
                if (fullk) { float4 v = *(const float4*)ap; x0 = v.x; x1 = v.y; x2 = v.z; x3 = v.w; }
                else {
                    if (kk     < K) x0 = ap[0];
                    if (kk + 1 < K) x1 = ap[1];
                    if (kk + 2 < K) x2 = ap[2];
                    if (kk + 3 < K) x3 = ap[3];
                }
            }
            unsigned u0 = __float_as_uint(x0), u1 = __float_as_uint(x1);
            unsigned u2 = __float_as_uint(x2), u3 = __float_as_uint(x3);
            uint2 hp; hp.x = (u1 & 0xFFFF0000u) | (u0 >> 16);
                      hp.y = (u3 & 0xFFFF0000u) | (u2 >> 16);
            float l0 = x0 - __uint_as_float(u0 & 0xFFFF0000u);
            float l1 = x1 - __uint_as_float(u1 & 0xFFFF0000u);
            float l2 = x2 - __uint_as_float(u2 & 0xFFFF0000u);
            float l3 = x3 - __uint_as_float(u3 & 0xFFFF0000u);
            uint2 lp; lp.x = (__float_as_uint(l1) & 0xFFFF0000u) | (__float_as_uint(l0) >> 16);
                      lp.y = (__float_as_uint(l3) & 0xFFFF0000u) | (__float_as_uint(l2) >> 16);
            *(uint2*)&sAh[r * 40 + kb] = hp;
            *(uint2*)&sAl[r * 40 + kb] = lp;
        }
        __syncthreads();

        short8 ah = *(const short8*)&sAh[(wr + fr) * 40 + ko];
        short8 al = *(const short8*)&sAl[(wr + fr) * 40 + ko];
#pragma unroll
        for (int j = 0; j < MT; ++j) {
            short8 bh = *(const short8*)&sWh[(j * 16 + fr) * 40 + ko];
            short8 bl = *(const short8*)&sWl[(j * 16 + fr) * 40 + ko];
            acc[j] = __builtin_amdgcn_mfma_f32_16x16x32_bf16(al, bh, acc[j], 0, 0, 0);
            acc[j] = __builtin_amdgcn_mfma_f32_16x16x32_bf16(ah, bl, acc[j], 0, 0, 0);
            acc[j] = __builtin_amdgcn_mfma_f32_16x16x32_bf16(ah, bh, acc[j], 0, 0, 0);
        }
        __syncthreads();
    }

    // epilogue: C/D layout col=lane&15, row=(lane>>4)*4+q  [m89-verified]
#pragma unroll
    for (int j = 0; j < MT; ++j) {
        int col = j * 16 + fr;
        if (col >= M) continue;
        int row0 = rowBase + wr + (lane >> 4) * 4;
        float bv = bias ? bias[col] : 0.f;
#pragma unroll
        for (int q = 0; q < 4; q++) {
            int r = row0 + q;
            if (r >= n) break;
            float v = cAB * acc[j][q] + bv;
            if (cA != 0.f) v += cA * A[(size_t)r * K + col];  // only when M==K
            C[(size_t)r * M + col] = v;
            if (Cs) Cs[(size_t)r * SS + col] = (_Float16)v;
        }
    }
}

// ---- prop: out = cP*(D^-1/2 A D^-1/2 h) + cH*h + bias ; gather from fp16 shadow ----
__global__ __launch_bounds__(256)
void prop_kernel(const float* __restrict__ h, const _Float16* __restrict__ hs,
                 float* __restrict__ out, _Float16* __restrict__ outs,
                 const int* __restrict__ rowptr, const int* __restrict__ csr_src,
                 const float* __restrict__ csr_w, const float* __restrict__ dinv,
                 const float* __restrict__ bias, int n, int D, float cP, float cH) {
    int i = (blockIdx.x * blockDim.x + threadIdx.x) >> 6;
    int lane = threadIdx.x & 63;
    int c = lane * 4;
    if (i >= n || c >= D) return;
    int D4 = D >> 2;
    long bi = (long)i * D4 + lane;
    const float4* h4 = (const float4*)h;
    float4 hv = h4[bi];
    float sw = dinv[i] * dinv[i];
    float4 acc = {sw * hv.x, sw * hv.y, sw * hv.z, sw * hv.w};
    int p0 = rowptr[i], p1 = rowptr[i + 1];
    for (int p = p0; p < p1; ++p) {
        int s = csr_src[p];
        float w = csr_w[p];
        hf4 v = *(const hf4*)&hs[(size_t)s * SS + c];
        acc.x += w * (float)v[0];
        acc.y += w * (float)v[1];
        acc.z += w * (float)v[2];
        acc.w += w * (float)v[3];
    }
    float4 r = {cP * acc.x, cP * acc.y, cP * acc.z, cP * acc.w};
    if (cH != 0.f) { r.x += cH * hv.x; r.y += cH * hv.y; r.z += cH * hv.z; r.w += cH * hv.w; }
    if (bias) { float4 b = ((const float4*)bias)[lane]; r.x += b.x; r.y += b.y; r.z += b.z; r.w += b.w; }
    ((float4*)out)[bi] = r;
    if (outs) {
        hf4 o; o[0] = (_Float16)r.x; o[1] = (_Float16)r.y; o[2] = (_Float16)r.z; o[3] = (_Float16)r.w;
        *(hf4*)&outs[(size_t)i * SS + c] = o;
    }
}

// ---------------- GATv2 ----------------
__device__ inline float lrelu(float x) { return x > 0.f ? x : NEG_SLOPE * x; }

__global__ __launch_bounds__(256)
void gat_logits_kernel(const float* __restrict__ xl, const _Float16* __restrict__ xls,
                       const float* __restrict__ xr, const float* __restrict__ att,
                       const int* __restrict__ rowptr, const int* __restrict__ csr_src,
                       float* __restrict__ logits, float* __restrict__ self_logits, int n) {
    int t = blockIdx.x * blockDim.x + threadIdx.x;
    int i = t >> 1, hh = t & 1;
    if (i >= n) return;
    float4 attv[8], xrv[8];
    const float4* att4 = (const float4*)att;
    const float4* xr4 = (const float4*)xr;
#pragma unroll
    for (int c = 0; c < 8; c++) {
        attv[c] = att4[hh * 8 + c];
        xrv[c]  = xr4[(long)i * 16 + hh * 8 + c];
    }
    {
        const float4* xl4 = (const float4*)xl;
        float s = 0.f;
        long b = (long)i * 16 + hh * 8;
#pragma unroll
        for (int c = 0; c < 8; c++) {
            float4 e = xl4[b + c];
            s += lrelu(e.x + xrv[c].x) * attv[c].x;
            s += lrelu(e.y + xrv[c].y) * attv[c].y;
            s += lrelu(e.z + xrv[c].z) * attv[c].z;
            s += lrelu(e.w + xrv[c].w) * attv[c].w;
        }
        self_logits[i * 2 + hh] = s;
    }
    int p0 = rowptr[i], p1 = rowptr[i + 1];
    for (int p = p0; p < p1; ++p) {
        int sn = csr_src[p];
        size_t b = (size_t)sn * SS + hh * 32;
        float s = 0.f;
#pragma unroll
        for (int c = 0; c < 8; c++) {
            hf4 e = *(const hf4*)&xls[b + c * 4];
            s += lrelu((float)e[0] + xrv[c].x) * attv[c].x;
            s += lrelu((float)e[1] + xrv[c].y) * attv[c].y;
            s += lrelu((float)e[2] + xrv[c].z) * attv[c].z;
            s += lrelu((float)e[3] + xrv[c].w) * attv[c].w;
        }
        logits[(long)p * 2 + hh] = s;
    }
}

__global__ __launch_bounds__(256)
void gat_mden_kernel(const float* __restrict__ logits, const float* __restrict__ self_logits,
                     const int* __restrict__ rowptr, float* __restrict__ m_arr,
                     float* __restrict__ den_arr, int n) {
    int t = blockIdx.x * blockDim.x + threadIdx.x;
    int i = t >> 1, hh = t & 1;
    if (i >= n) return;
    int p0 = rowptr[i], p1 = rowptr[i + 1];
    float m = self_logits[i * 2 + hh];
    for (int p = p0; p < p1; ++p) m = fmaxf(m, logits[(long)p * 2 + hh]);
    float den = expf(self_logits[i * 2 + hh] - m);
    for (int p = p0; p < p1; ++p) den += expf(logits[(long)p * 2 + hh] - m);
    m_arr[i * 2 + hh] = m;
    den_arr[i * 2 + hh] = den;
}

__global__ __launch_bounds__(256)
void gat_out_kernel(const float* __restrict__ xl, const _Float16* __restrict__ xls,
                    const int* __restrict__ rowptr, const int* __restrict__ csr_src,
                    const float* __restrict__ logits, const float* __restrict__ self_logits,
                    const float* __restrict__ m_arr, const float* __restrict__ den_arr,
                    const float* __restrict__ bias, float* __restrict__ out,
                    _Float16* __restrict__ outs, int n) {
    int i = (blockIdx.x * blockDim.x + threadIdx.x) >> 6;
    int lane = threadIdx.x & 63;
    if (i >= n) return;
    int hh = lane >> 5;
    float m = m_arr[i * 2 + hh];
    float inv = 1.f / (den_arr[i * 2 + hh] + 1e-16f);
    float acc = expf(self_logits[i * 2 + hh] - m) * inv * xl[(long)i * 64 + lane];
    int p0 = rowptr[i], p1 = rowptr[i + 1];
    for (int p = p0; p < p1; ++p) {
        float w = expf(logits[(long)p * 2 + hh] - m) * inv;
        acc += w * (float)xls[(size_t)csr_src[p] * SS + lane];
    }
    float r = fmaxf(acc + bias[lane], 0.f);   // bias + ReLU fused
    out[(long)i * 64 + lane] = r;
    outs[(size_t)i * SS + lane] = (_Float16)r;
}

__global__ void sigmoid_kernel(const float* __restrict__ in, float* __restrict__ out, int n4) {
    int i = blockIdx.x * blockDim.x + threadIdx.x;
    if (i < n4) {
        float4 v = ((const float4*)in)[i];
        float4 r;
        r.x = 1.f / (1.f + expf(-v.x));
        r.y = 1.f / (1.f + expf(-v.y));
        r.z = 1.f / (1.f + expf(-v.z));
        r.w = 1.f / (1.f + expf(-v.w));
        ((float4*)out)[i] = r;
    }
}

// ---------------- launch ----------------
extern "C" void kernel_launch(void* const* d_in, const int* in_sizes, int n_in,
                              void* d_out, int out_size, void* d_ws, size_t ws_size,
                              hipStream_t stream) {
    const int N = NN;
    const int E = in_sizes[1] / 2;

    struct WSpec { int idx; int K, M; };
    const WSpec wspec[11] = {
        {2, 300, 256},   // W1
        {4, 256, 256},   // W2
        {5, 256, 128},   // W3
        {7, 128, 64},    // W4
        {9, 64, 32},     // W5
        {11, 32, 64},    // Wl
        {12, 32, 64},    // Wr
        {15, 64, 128},   // Wd1
        {17, 128, 256},  // Wd2
        {19, 256, 256},  // Wd3
        {20, 256, 300},  // Wd4
    };
    size_t arena_elems = 0;
    int kp[11], mp[11];
    size_t woff[11];
    for (int i = 0; i < 11; i++) {
        kp[i] = (wspec[i].K + 31) & ~31;
        mp[i] = (wspec[i].M + 63) & ~63;
        woff[i] = arena_elems;
        arena_elems += (size_t)2 * mp[i] * kp[i];
    }

    size_t need = 0;
    need += (size_t)N * 304 * 4 * 2;     // bufA, bufB
    need += (size_t)N * SS * 2;          // fp16 shadow
    need += (size_t)E * 4;               // csr_w
    need += (size_t)E * 2 * 4;           // logits
    need += (size_t)N * 2 * 4 * 3;       // self_logits, m_arr, den_arr
    need += (size_t)N * 4;               // dinv
    need += (size_t)N * 4;               // deg
    need += (size_t)(N + 4) * 4;         // rowptr
    need += (size_t)N * 4;               // cursor
    need += (size_t)E * 4;               // csr_src
    need += arena_elems * 2 + 128;       // bf16 weight arena + align slack
    if (ws_size < need) return;

    const float* x      = (const float*)d_in[0];
    const int*   ei     = (const int*)d_in[1];
    const int*   e_src  = ei;
    const int*   e_dst  = ei + E;
    const float* b1  = (const float*)d_in[3];
    const float* b3  = (const float*)d_in[6];
    const float* b4  = (const float*)d_in[8];
    const float* b5  = (const float*)d_in[10];
    const float* attw= (const float*)d_in[13];
    const float* bg  = (const float*)d_in[14];
    const float* bd1 = (const float*)d_in[16];
    const float* bd2 = (const float*)d_in[18];
    const float* bd4 = (const float*)d_in[21];

    char* w = (char*)d_ws;
    float* bufA = (float*)w;                 w += (size_t)N * 304 * 4;
    float* bufB = (float*)w;                 w += (size_t)N * 304 * 4;
    _Float16* S = (_Float16*)w;              w += (size_t)N * SS * 2;
    float* csr_w = (float*)w;                w += (size_t)E * 4;
    float* logits = (float*)w;               w += (size_t)E * 2 * 4;
    float* self_logits = (float*)w;          w += (size_t)N * 2 * 4;
    float* m_arr = (float*)w;                w += (size_t)N * 2 * 4;
    float* den_arr = (float*)w;              w += (size_t)N * 2 * 4;
    float* dinv = (float*)w;                 w += (size_t)N * 4;
    int* deg = (int*)w;                      w += (size_t)N * 4;
    int* rowptr = (int*)w;                   w += (size_t)(N + 4) * 4;
    int* cursor = (int*)w;                   w += (size_t)N * 4;
    int* csr_src = (int*)w;                  w += (size_t)E * 4;
    w = (char*)(((size_t)w + 63) & ~(size_t)63);
    u16* arena = (u16*)w;                    w += arena_elems * 2;
    float* T = (float*)d_out;                // GEMM tmp buffer (N x <=300)

    int nb_e = (E + 255) / 256;
    int nb_n = (N + 255) / 256;
    int nb_wave = (N + 3) / 4;
    int nb_2n = (2 * N + 255) / 256;

    for (int i = 0; i < 11; i++) {
        int total = mp[i] * kp[i];
        splitw_kernel<<<(total + 255) / 256, 256, 0, stream>>>(
            (const float*)d_in[wspec[i].idx], arena + woff[i], arena + woff[i] + total,
            wspec[i].K, wspec[i].M, kp[i], total);
    }

    hipMemsetAsync(deg, 0, (size_t)N * 4, stream);
    hist_kernel<<<nb_e, 256, 0, stream>>>(e_dst, deg, E);
    scan_kernel<<<1, 1024, 0, stream>>>(deg, rowptr, N);
    dinv_kernel<<<nb_n, 256, 0, stream>>>(deg, dinv, N);
    copy_int_kernel<<<nb_n, 256, 0, stream>>>(rowptr, cursor, N);
    fill_kernel<<<nb_e, 256, 0, stream>>>(e_src, e_dst, dinv, cursor, csr_src, csr_w, E);

    const int GR = (N + 63) / 64;
    auto gemm = [&](int wi, const float* A, float* C, float cAB, float cA,
                    const float* bias, bool shadow) {
        int K = wspec[wi].K, M = wspec[wi].M;
        int total = mp[wi] * kp[wi];
        const u16* wh = arena + woff[wi];
        const u16* wl = arena + woff[wi] + total;
        _Float16* Cs = shadow ? S : nullptr;
        int mt = mp[wi] / 16;
        switch (mt) {
            case 4:  gemm_allm_kernel<4><<<GR, 256, 0, stream>>>(A, wh, wl, C, Cs, N, K, M, kp[wi], cAB, cA, bias); break;
            case 8:  gemm_allm_kernel<8><<<GR, 256, 0, stream>>>(A, wh, wl, C, Cs, N, K, M, kp[wi], cAB, cA, bias); break;
            case 16: gemm_allm_kernel<16><<<GR, 256, 0, stream>>>(A, wh, wl, C, Cs, N, K, M, kp[wi], cAB, cA, bias); break;
            default: gemm_allm_kernel<20><<<GR, 256, 0, stream>>>(A, wh, wl, C, Cs, N, K, M, kp[wi], cAB, cA, bias); break;
        }
    };
    auto prop = [&](const float* h, float* out, int D, float cP, float cH,
                    const float* bias, bool shadow) {
        prop_kernel<<<nb_wave, 256, 0, stream>>>(h, S, out, shadow ? S : nullptr,
                                                 rowptr, csr_src, csr_w, dinv,
                                                 bias, N, D, cP, cH);
    };

    // L1: gcn(x, W1, b1) -> A [256]
    gemm(0, x, T, 1.f, 0.f, nullptr, true);
    prop(T, bufA, 256, 1.f, 0.f, b1, true);
    // L2: gcn2(A, W2) -> A
    prop(bufA, bufB, 256, 1.f - ALPHA_C, ALPHA_C, nullptr, false);
    gemm(1, bufB, bufA, BETA_C, 1.f - BETA_C, nullptr, false);
    // L3: gcn(A, W3, b3) -> B [128]
    gemm(2, bufA, T, 1.f, 0.f, nullptr, true);
    prop(T, bufB, 128, 1.f, 0.f, b3, false);
    // L4: gcn(B, W4, b4) -> A [64]
    gemm(3, bufB, T, 1.f, 0.f, nullptr, true);
    prop(T, bufA, 64, 1.f, 0.f, b4, false);
    // L5: gcn(A, W5, b5) -> B [32]
    gemm(4, bufA, T, 1.f, 0.f, nullptr, true);
    prop(T, bufB, 32, 1.f, 0.f, b5, false);
    // GAT: xl = B@Wl -> A (+S), xr = B@Wr -> T
    gemm(5, bufB, bufA, 1.f, 0.f, nullptr, true);
    gemm(6, bufB, T, 1.f, 0.f, nullptr, false);
    gat_logits_kernel<<<nb_2n, 256, 0, stream>>>(bufA, S, T, attw, rowptr, csr_src,
                                                 logits, self_logits, N);
    gat_mden_kernel<<<nb_2n, 256, 0, stream>>>(logits, self_logits, rowptr, m_arr, den_arr, N);
    gat_out_kernel<<<nb_wave, 256, 0, stream>>>(bufA, S, rowptr, csr_src, logits, self_logits,
                                                m_arr, den_arr, bg, bufB, S, N);  // B [64] + S
    // dec1: prop@64 then gemm 64->128 (+bd1)   [prop/gemm commute]
    prop(bufB, bufA, 64, 1.f, 0.f, nullptr, false);
    gemm(7, bufA, T, 1.f, 0.f, bd1, true);
    // dec2: prop@128 then gemm 128->256 (+bd2)
    prop(T, bufB, 128, 1.f, 0.f, nullptr, false);
    gemm(8, bufB, bufA, 1.f, 0.f, bd2, true);
    // dec3: gcn2(A, Wd3) -> A
    prop(bufA, bufB, 256, 1.f - ALPHA_C, ALPHA_C, nullptr, false);
    gemm(9, bufB, bufA, BETA_C, 1.f - BETA_C, nullptr, true);
    // dec4: prop@256 then gemm 256->300 (+bd4)
    prop(bufA, bufB, 256, 1.f, 0.f, nullptr, false);
    gemm(10, bufB, T, 1.f, 0.f, bd4, false);
    // sigmoid in-place on d_out
    sigmoid_kernel<<<(out_size / 4 + 255) / 256, 256, 0, stream>>>(T, (float*)d_out, out_size / 4);
}

// Round 9
// 1326.026 us; speedup vs baseline: 1.6815x; 1.6815x over previous
//
#include <hip/hip_runtime.h>
#include <math.h>

#define NN 50000
#define FIN 300
#define SS 304   // fp16 shadow row stride (halves)
constexpr float ALPHA_C = 0.5f;
constexpr float BETA_C  = 0.09531017980432486f;  // log(1.1)
constexpr float NEG_SLOPE = 0.2f;

typedef unsigned short u16;
typedef __attribute__((ext_vector_type(8))) short short8;
typedef __attribute__((ext_vector_type(4))) float f32x4;
typedef _Float16 hf4 __attribute__((ext_vector_type(4)));

// ---------------- CSR build ----------------
__global__ void hist_kernel(const int* __restrict__ dst, int* __restrict__ deg, int E) {
    int e = blockIdx.x * blockDim.x + threadIdx.x;
    if (e < E) atomicAdd(&deg[dst[e]], 1);
}

__global__ void scan_kernel(const int* __restrict__ deg, int* __restrict__ rowptr, int n) {
    __shared__ int sh[1024];
    __shared__ int carry;
    if (threadIdx.x == 0) { carry = 0; rowptr[0] = 0; }
    __syncthreads();
    for (int base = 0; base < n; base += 1024) {
        int i = base + threadIdx.x;
        int v = (i < n) ? deg[i] : 0;
        sh[threadIdx.x] = v;
        __syncthreads();
        for (int off = 1; off < 1024; off <<= 1) {
            int t = (threadIdx.x >= off) ? sh[threadIdx.x - off] : 0;
            __syncthreads();
            sh[threadIdx.x] += t;
            __syncthreads();
        }
        if (i < n) rowptr[i + 1] = sh[threadIdx.x] + carry;
        __syncthreads();
        if (threadIdx.x == 0) carry += sh[1023];
        __syncthreads();
    }
}

__global__ void dinv_kernel(const int* __restrict__ deg, float* __restrict__ dinv, int n) {
    int i = blockIdx.x * blockDim.x + threadIdx.x;
    if (i < n) dinv[i] = rsqrtf((float)deg[i] + 1.0f);
}

__global__ void copy_int_kernel(const int* __restrict__ a, int* __restrict__ b, int n) {
    int i = blockIdx.x * blockDim.x + threadIdx.x;
    if (i < n) b[i] = a[i];
}

__global__ void fill_kernel(const int* __restrict__ src, const int* __restrict__ dst,
                            const float* __restrict__ dinv, int* __restrict__ cursor,
                            int* __restrict__ csr_src, float* __restrict__ csr_w, int E) {
    int e = blockIdx.x * blockDim.x + threadIdx.x;
    if (e < E) {
        int s = src[e], d = dst[e];
        int p = atomicAdd(&cursor[d], 1);
        csr_src[p] = s;
        csr_w[p]   = dinv[s] * dinv[d];
    }
}

// ---------------- weight split: W[k][c] -> WhT/WlT [c][k] bf16, zero-padded ----------------
__global__ void splitw_kernel(const float* __restrict__ W, u16* __restrict__ WhT,
                              u16* __restrict__ WlT, int K, int M, int Kp, int total) {
    int t = blockIdx.x * blockDim.x + threadIdx.x;
    if (t >= total) return;
    int c = t / Kp, k = t - c * Kp;
    float x = (c < M && k < K) ? W[(size_t)k * M + c] : 0.f;
    unsigned u = __float_as_uint(x);
    WhT[t] = (u16)(u >> 16);
    float lo = x - __uint_as_float(u & 0xFFFF0000u);
    WlT[t] = (u16)(__float_as_uint(lo) >> 16);
}

// ---------------- MFMA GEMM (64x64 tile, XCD-swizzled 1D grid) ----------------
// C = cAB*(A@W) + cA*A + bias; optional fp16 shadow. Markidis 3-term.
// Linear grid: wgid = bijective XCD swizzle (m204); col = wgid%gx (A-panel-sharing
// blocks contiguous -> same XCD L2 -> A fetched ~once from HBM).
__global__ __launch_bounds__(256)
void gemm_mfma_kernel(const float* __restrict__ A, const u16* __restrict__ WhT,
                      const u16* __restrict__ WlT, float* __restrict__ C,
                      _Float16* __restrict__ Cs, int n, int K, int M, int Kp,
                      float cAB, float cA, const float* __restrict__ bias, int gx) {
    __shared__ u16 sAh[64 * 40], sAl[64 * 40], sWh[64 * 40], sWl[64 * 40];
    const int tid = threadIdx.x;
    // m204 bijective XCD swizzle
    const int nwg = gridDim.x;
    const int q = nwg >> 3, r = nwg & 7;
    const int xcd = blockIdx.x & 7, off = blockIdx.x >> 3;
    const int wgid = (xcd < r ? xcd * (q + 1) : r * (q + 1) + (xcd - r) * q) + off;
    const int colBase = (wgid % gx) * 64;
    const int rowBase = (wgid / gx) * 64;
    const int lane = tid & 63, wid = tid >> 6;
    const int wr = (wid >> 1) * 32, wc = (wid & 1) * 32;
    const int fr = lane & 15, ko = (lane >> 4) * 8;
    const int wsc = tid >> 2, wsk = (tid & 3) * 8;

    f32x4 acc[2][2] = {};

    for (int k0 = 0; k0 < Kp; k0 += 32) {
        {
            size_t g = (size_t)(colBase + wsc) * Kp + k0 + wsk;
            *(uint4*)&sWh[wsc * 40 + wsk] = *(const uint4*)&WhT[g];
            *(uint4*)&sWl[wsc * 40 + wsk] = *(const uint4*)&WlT[g];
        }
        const bool fullk = (k0 + 32 <= K);
        for (int s = tid; s < 512; s += 256) {
            int rr = s >> 3, kb = (s & 7) * 4;
            int gr = rowBase + rr, kk = k0 + kb;
            float x0 = 0.f, x1 = 0.f, x2 = 0.f, x3 = 0.f;
            if (gr < n) {
                const float* ap = A + (size_t)gr * K + kk;
                if (fullk) { float4 v = *(const float4*)ap; x0 = v.x; x1 = v.y; x2 = v.z; x3 = v.w; }
                else {
                    if (kk     < K) x0 = ap[0];
                    if (kk + 1 < K) x1 = ap[1];
                    if (kk + 2 < K) x2 = ap[2];
                    if (kk + 3 < K) x3 = ap[3];
                }
            }
            unsigned u0 = __float_as_uint(x0), u1 = __float_as_uint(x1);
            unsigned u2 = __float_as_uint(x2), u3 = __float_as_uint(x3);
            uint2 hp; hp.x = (u1 & 0xFFFF0000u) | (u0 >> 16);
                      hp.y = (u3 & 0xFFFF0000u) | (u2 >> 16);
            float l0 = x0 - __uint_as_float(u0 & 0xFFFF0000u);
            float l1 = x1 - __uint_as_float(u1 & 0xFFFF0000u);
            float l2 = x2 - __uint_as_float(u2 & 0xFFFF0000u);
            float l3 = x3 - __uint_as_float(u3 & 0xFFFF0000u);
            uint2 lp; lp.x = (__float_as_uint(l1) & 0xFFFF0000u) | (__float_as_uint(l0) >> 16);
                      lp.y = (__float_as_uint(l3) & 0xFFFF0000u) | (__float_as_uint(l2) >> 16);
            *(uint2*)&sAh[rr * 40 + kb] = hp;
            *(uint2*)&sAl[rr * 40 + kb] = lp;
        }
        __syncthreads();

        short8 ah[2], al[2], bh[2], bl[2];
        ah[0] = *(const short8*)&sAh[(wr +      fr) * 40 + ko];
        ah[1] = *(const short8*)&sAh[(wr + 16 + fr) * 40 + ko];
        al[0] = *(const short8*)&sAl[(wr +      fr) * 40 + ko];
        al[1] = *(const short8*)&sAl[(wr + 16 + fr) * 40 + ko];
        bh[0] = *(const short8*)&sWh[(wc +      fr) * 40 + ko];
        bh[1] = *(const short8*)&sWh[(wc + 16 + fr) * 40 + ko];
        bl[0] = *(const short8*)&sWl[(wc +      fr) * 40 + ko];
        bl[1] = *(const short8*)&sWl[(wc + 16 + fr) * 40 + ko];
#pragma unroll
        for (int i = 0; i < 2; i++)
#pragma unroll
            for (int j = 0; j < 2; j++) {
                acc[i][j] = __builtin_amdgcn_mfma_f32_16x16x32_bf16(al[i], bh[j], acc[i][j], 0, 0, 0);
                acc[i][j] = __builtin_amdgcn_mfma_f32_16x16x32_bf16(ah[i], bl[j], acc[i][j], 0, 0, 0);
                acc[i][j] = __builtin_amdgcn_mfma_f32_16x16x32_bf16(ah[i], bh[j], acc[i][j], 0, 0, 0);
            }
        __syncthreads();
    }

    // epilogue: C/D layout col=lane&15, row=(lane>>4)*4+q  [m89-verified]
#pragma unroll
    for (int i = 0; i < 2; i++)
#pragma unroll
        for (int j = 0; j < 2; j++) {
            int row0 = rowBase + wr + i * 16 + (lane >> 4) * 4;
            int col  = colBase + wc + j * 16 + fr;
            if (col >= M) continue;
            float bv = bias ? bias[col] : 0.f;
#pragma unroll
            for (int qq = 0; qq < 4; qq++) {
                int rr = row0 + qq;
                if (rr >= n) break;
                float v = cAB * acc[i][j][qq] + bv;
                if (cA != 0.f) v += cA * A[(size_t)rr * K + col];
                C[(size_t)rr * M + col] = v;
                if (Cs) Cs[(size_t)rr * SS + col] = (_Float16)v;
            }
        }
}

// ---- prop: multi-node waves (64/(D/4) nodes per wave) + 4x-unrolled MLP gather ----
__global__ __launch_bounds__(256)
void prop_kernel(const float* __restrict__ h, const _Float16* __restrict__ hs,
                 float* __restrict__ out, _Float16* __restrict__ outs,
                 const int* __restrict__ rowptr, const int* __restrict__ csr_src,
                 const float* __restrict__ csr_w, const float* __restrict__ dinv,
                 const float* __restrict__ bias, int n, int D, float cP, float cH) {
    int wv = (blockIdx.x * blockDim.x + threadIdx.x) >> 6;
    int lane = threadIdx.x & 63;
    int D4 = D >> 2;
    int npw = 64 / D4;                 // nodes per wave: 1,2,4,8
    int sub = lane / D4;               // which node within the wave
    int cl = lane - sub * D4;          // col-quad index
    int i = wv * npw + sub;
    if (i >= n) return;
    int c = cl * 4;
    long bi = (long)i * D4 + cl;
    const float4* h4 = (const float4*)h;
    float4 hv = h4[bi];
    float sw = dinv[i] * dinv[i];
    float4 a0 = {sw * hv.x, sw * hv.y, sw * hv.z, sw * hv.w};
    float4 a1 = {0,0,0,0}, a2 = {0,0,0,0}, a3 = {0,0,0,0};
    int p0 = rowptr[i], p1 = rowptr[i + 1];
    int p = p0;
    for (; p + 4 <= p1; p += 4) {
        int s0 = csr_src[p], s1 = csr_src[p+1], s2 = csr_src[p+2], s3 = csr_src[p+3];
        float w0 = csr_w[p], w1 = csr_w[p+1], w2 = csr_w[p+2], w3 = csr_w[p+3];
        hf4 v0 = *(const hf4*)&hs[(size_t)s0 * SS + c];
        hf4 v1 = *(const hf4*)&hs[(size_t)s1 * SS + c];
        hf4 v2 = *(const hf4*)&hs[(size_t)s2 * SS + c];
        hf4 v3 = *(const hf4*)&hs[(size_t)s3 * SS + c];
        a0.x += w0*(float)v0[0]; a0.y += w0*(float)v0[1]; a0.z += w0*(float)v0[2]; a0.w += w0*(float)v0[3];
        a1.x += w1*(float)v1[0]; a1.y += w1*(float)v1[1]; a1.z += w1*(float)v1[2]; a1.w += w1*(float)v1[3];
        a2.x += w2*(float)v2[0]; a2.y += w2*(float)v2[1]; a2.z += w2*(float)v2[2]; a2.w += w2*(float)v2[3];
        a3.x += w3*(float)v3[0]; a3.y += w3*(float)v3[1]; a3.z += w3*(float)v3[2]; a3.w += w3*(float)v3[3];
    }
    for (; p < p1; ++p) {
        int s = csr_src[p];
        float w = csr_w[p];
        hf4 v = *(const hf4*)&hs[(size_t)s * SS + c];
        a0.x += w*(float)v[0]; a0.y += w*(float)v[1]; a0.z += w*(float)v[2]; a0.w += w*(float)v[3];
    }
    float4 acc = {a0.x + a1.x + a2.x + a3.x, a0.y + a1.y + a2.y + a3.y,
                  a0.z + a1.z + a2.z + a3.z, a0.w + a1.w + a2.w + a3.w};
    float4 rr = {cP * acc.x, cP * acc.y, cP * acc.z, cP * acc.w};
    if (cH != 0.f) { rr.x += cH * hv.x; rr.y += cH * hv.y; rr.z += cH * hv.z; rr.w += cH * hv.w; }
    if (bias) { float4 b = ((const float4*)bias)[cl]; rr.x += b.x; rr.y += b.y; rr.z += b.z; rr.w += b.w; }
    ((float4*)out)[bi] = rr;
    if (outs) {
        hf4 o; o[0] = (_Float16)rr.x; o[1] = (_Float16)rr.y; o[2] = (_Float16)rr.z; o[3] = (_Float16)rr.w;
        *(hf4*)&outs[(size_t)i * SS + c] = o;
    }
}

// ---------------- GATv2 ----------------
__device__ inline float lrelu(float x) { return x > 0.f ? x : NEG_SLOPE * x; }

__global__ __launch_bounds__(256)
void gat_logits_kernel(const float* __restrict__ xl, const _Float16* __restrict__ xls,
                       const float* __restrict__ xr, const float* __restrict__ att,
                       const int* __restrict__ rowptr, const int* __restrict__ csr_src,
                       float* __restrict__ logits, float* __restrict__ self_logits, int n) {
    int t = blockIdx.x * blockDim.x + threadIdx.x;
    int i = t >> 1, hh = t & 1;
    if (i >= n) return;
    float4 attv[8], xrv[8];
    const float4* att4 = (const float4*)att;
    const float4* xr4 = (const float4*)xr;
#pragma unroll
    for (int c = 0; c < 8; c++) {
        attv[c] = att4[hh * 8 + c];
        xrv[c]  = xr4[(long)i * 16 + hh * 8 + c];
    }
    {
        const float4* xl4 = (const float4*)xl;
        float s = 0.f;
        long b = (long)i * 16 + hh * 8;
#pragma unroll
        for (int c = 0; c < 8; c++) {
            float4 e = xl4[b + c];
            s += lrelu(e.x + xrv[c].x) * attv[c].x;
            s += lrelu(e.y + xrv[c].y) * attv[c].y;
            s += lrelu(e.z + xrv[c].z) * attv[c].z;
            s += lrelu(e.w + xrv[c].w) * attv[c].w;
        }
        self_logits[i * 2 + hh] = s;
    }
    int p0 = rowptr[i], p1 = rowptr[i + 1];
    for (int p = p0; p < p1; ++p) {
        int sn = csr_src[p];
        size_t b = (size_t)sn * SS + hh * 32;
        float s = 0.f;
#pragma unroll
        for (int c = 0; c < 8; c++) {
            hf4 e = *(const hf4*)&xls[b + c * 4];
            s += lrelu((float)e[0] + xrv[c].x) * attv[c].x;
            s += lrelu((float)e[1] + xrv[c].y) * attv[c].y;
            s += lrelu((float)e[2] + xrv[c].z) * attv[c].z;
            s += lrelu((float)e[3] + xrv[c].w) * attv[c].w;
        }
        logits[(long)p * 2 + hh] = s;
    }
}

__global__ __launch_bounds__(256)
void gat_mden_kernel(const float* __restrict__ logits, const float* __restrict__ self_logits,
                     const int* __restrict__ rowptr, float* __restrict__ m_arr,
                     float* __restrict__ den_arr, int n) {
    int t = blockIdx.x * blockDim.x + threadIdx.x;
    int i = t >> 1, hh = t & 1;
    if (i >= n) return;
    int p0 = rowptr[i], p1 = rowptr[i + 1];
    float m = self_logits[i * 2 + hh];
    for (int p = p0; p < p1; ++p) m = fmaxf(m, logits[(long)p * 2 + hh]);
    float den = expf(self_logits[i * 2 + hh] - m);
    for (int p = p0; p < p1; ++p) den += expf(logits[(long)p * 2 + hh] - m);
    m_arr[i * 2 + hh] = m;
    den_arr[i * 2 + hh] = den;
}

__global__ __launch_bounds__(256)
void gat_out_kernel(const float* __restrict__ xl, const _Float16* __restrict__ xls,
                    const int* __restrict__ rowptr, const int* __restrict__ csr_src,
                    const float* __restrict__ logits, const float* __restrict__ self_logits,
                    const float* __restrict__ m_arr, const float* __restrict__ den_arr,
                    const float* __restrict__ bias, float* __restrict__ out,
                    _Float16* __restrict__ outs, int n) {
    int i = (blockIdx.x * blockDim.x + threadIdx.x) >> 6;
    int lane = threadIdx.x & 63;
    if (i >= n) return;
    int hh = lane >> 5;
    float m = m_arr[i * 2 + hh];
    float inv = 1.f / (den_arr[i * 2 + hh] + 1e-16f);
    float acc = expf(self_logits[i * 2 + hh] - m) * inv * xl[(long)i * 64 + lane];
    int p0 = rowptr[i], p1 = rowptr[i + 1];
    for (int p = p0; p < p1; ++p) {
        float w = expf(logits[(long)p * 2 + hh] - m) * inv;
        acc += w * (float)xls[(size_t)csr_src[p] * SS + lane];
    }
    float r = fmaxf(acc + bias[lane], 0.f);
    out[(long)i * 64 + lane] = r;
    outs[(size_t)i * SS + lane] = (_Float16)r;
}

__global__ void sigmoid_kernel(const float* __restrict__ in, float* __restrict__ out, int n4) {
    int i = blockIdx.x * blockDim.x + threadIdx.x;
    if (i < n4) {
        float4 v = ((const float4*)in)[i];
        float4 r;
        r.x = 1.f / (1.f + expf(-v.x));
        r.y = 1.f / (1.f + expf(-v.y));
        r.z = 1.f / (1.f + expf(-v.z));
        r.w = 1.f / (1.f + expf(-v.w));
        ((float4*)out)[i] = r;
    }
}

// ---------------- launch ----------------
extern "C" void kernel_launch(void* const* d_in, const int* in_sizes, int n_in,
                              void* d_out, int out_size, void* d_ws, size_t ws_size,
                              hipStream_t stream) {
    const int N = NN;
    const int E = in_sizes[1] / 2;

    struct WSpec { int idx; int K, M; };
    const WSpec wspec[11] = {
        {2, 300, 256},   // W1
        {4, 256, 256},   // W2
        {5, 256, 128},   // W3
        {7, 128, 64},    // W4
        {9, 64, 32},     // W5
        {11, 32, 64},    // Wl
        {12, 32, 64},    // Wr
        {15, 64, 128},   // Wd1
        {17, 128, 256},  // Wd2
        {19, 256, 256},  // Wd3
        {20, 256, 300},  // Wd4
    };
    size_t arena_elems = 0;
    int kp[11], mp[11];
    size_t woff[11];
    for (int i = 0; i < 11; i++) {
        kp[i] = (wspec[i].K + 31) & ~31;
        mp[i] = (wspec[i].M + 63) & ~63;
        woff[i] = arena_elems;
        arena_elems += (size_t)2 * mp[i] * kp[i];
    }

    size_t need = 0;
    need += (size_t)N * 304 * 4 * 2;     // bufA, bufB
    need += (size_t)N * SS * 2;          // fp16 shadow
    need += (size_t)E * 4;               // csr_w
    need += (size_t)E * 2 * 4;           // logits
    need += (size_t)N * 2 * 4 * 3;       // self_logits, m_arr, den_arr
    need += (size_t)N * 4;               // dinv
    need += (size_t)N * 4;               // deg
    need += (size_t)(N + 4) * 4;         // rowptr
    need += (size_t)N * 4;               // cursor
    need += (size_t)E * 4;               // csr_src
    need += arena_elems * 2 + 128;       // bf16 weight arena + align slack
    if (ws_size < need) return;

    const float* x      = (const float*)d_in[0];
    const int*   ei     = (const int*)d_in[1];
    const int*   e_src  = ei;
    const int*   e_dst  = ei + E;
    const float* b1  = (const float*)d_in[3];
    const float* b3  = (const float*)d_in[6];
    const float* b4  = (const float*)d_in[8];
    const float* b5  = (const float*)d_in[10];
    const float* attw= (const float*)d_in[13];
    const float* bg  = (const float*)d_in[14];
    const float* bd1 = (const float*)d_in[16];
    const float* bd2 = (const float*)d_in[18];
    const float* bd4 = (const float*)d_in[21];

    char* w = (char*)d_ws;
    float* bufA = (float*)w;                 w += (size_t)N * 304 * 4;
    float* bufB = (float*)w;                 w += (size_t)N * 304 * 4;
    _Float16* S = (_Float16*)w;              w += (size_t)N * SS * 2;
    float* csr_w = (float*)w;                w += (size_t)E * 4;
    float* logits = (float*)w;               w += (size_t)E * 2 * 4;
    float* self_logits = (float*)w;          w += (size_t)N * 2 * 4;
    float* m_arr = (float*)w;                w += (size_t)N * 2 * 4;
    float* den_arr = (float*)w;              w += (size_t)N * 2 * 4;
    float* dinv = (float*)w;                 w += (size_t)N * 4;
    int* deg = (int*)w;                      w += (size_t)N * 4;
    int* rowptr = (int*)w;                   w += (size_t)(N + 4) * 4;
    int* cursor = (int*)w;                   w += (size_t)N * 4;
    int* csr_src = (int*)w;                  w += (size_t)E * 4;
    w = (char*)(((size_t)w + 63) & ~(size_t)63);
    u16* arena = (u16*)w;                    w += arena_elems * 2;
    float* T = (float*)d_out;                // GEMM tmp buffer (N x <=300)

    int nb_e = (E + 255) / 256;
    int nb_n = (N + 255) / 256;
    int nb_wave = (N + 3) / 4;
    int nb_2n = (2 * N + 255) / 256;

    for (int i = 0; i < 11; i++) {
        int total = mp[i] * kp[i];
        splitw_kernel<<<(total + 255) / 256, 256, 0, stream>>>(
            (const float*)d_in[wspec[i].idx], arena + woff[i], arena + woff[i] + total,
            wspec[i].K, wspec[i].M, kp[i], total);
    }

    hipMemsetAsync(deg, 0, (size_t)N * 4, stream);
    hist_kernel<<<nb_e, 256, 0, stream>>>(e_dst, deg, E);
    scan_kernel<<<1, 1024, 0, stream>>>(deg, rowptr, N);
    dinv_kernel<<<nb_n, 256, 0, stream>>>(deg, dinv, N);
    copy_int_kernel<<<nb_n, 256, 0, stream>>>(rowptr, cursor, N);
    fill_kernel<<<nb_e, 256, 0, stream>>>(e_src, e_dst, dinv, cursor, csr_src, csr_w, E);

    auto gemm = [&](int wi, const float* A, float* C, float cAB, float cA,
                    const float* bias, bool shadow) {
        int K = wspec[wi].K, M = wspec[wi].M;
        int total = mp[wi] * kp[wi];
        int gx = (M + 63) / 64, gy = (N + 63) / 64;
        gemm_mfma_kernel<<<gx * gy, 256, 0, stream>>>(
            A, arena + woff[wi], arena + woff[wi] + total, C, shadow ? S : nullptr,
            N, K, M, kp[wi], cAB, cA, bias, gx);
    };
    auto prop = [&](const float* h, float* out, int D, float cP, float cH,
                    const float* bias, bool shadow) {
        int npw = 64 / (D >> 2);             // nodes per wave
        int npb = 4 * npw;                   // nodes per block (4 waves)
        int nb = (N + npb - 1) / npb;
        prop_kernel<<<nb, 256, 0, stream>>>(h, S, out, shadow ? S : nullptr,
                                            rowptr, csr_src, csr_w, dinv,
                                            bias, N, D, cP, cH);
    };

    // L1: gcn(x, W1, b1) -> A [256]
    gemm(0, x, T, 1.f, 0.f, nullptr, true);
    prop(T, bufA, 256, 1.f, 0.f, b1, true);
    // L2: gcn2(A, W2) -> A
    prop(bufA, bufB, 256, 1.f - ALPHA_C, ALPHA_C, nullptr, false);
    gemm(1, bufB, bufA, BETA_C, 1.f - BETA_C, nullptr, false);
    // L3: gcn(A, W3, b3) -> B [128]
    gemm(2, bufA, T, 1.f, 0.f, nullptr, true);
    prop(T, bufB, 128, 1.f, 0.f, b3, false);
    // L4: gcn(B, W4, b4) -> A [64]
    gemm(3, bufB, T, 1.f, 0.f, nullptr, true);
    prop(T, bufA, 64, 1.f, 0.f, b4, false);
    // L5: gcn(A, W5, b5) -> B [32]
    gemm(4, bufA, T, 1.f, 0.f, nullptr, true);
    prop(T, bufB, 32, 1.f, 0.f, b5, false);
    // GAT: xl = B@Wl -> A (+S), xr = B@Wr -> T
    gemm(5, bufB, bufA, 1.f, 0.f, nullptr, true);
    gemm(6, bufB, T, 1.f, 0.f, nullptr, false);
    gat_logits_kernel<<<nb_2n, 256, 0, stream>>>(bufA, S, T, attw, rowptr, csr_src,
                                                 logits, self_logits, N);
    gat_mden_kernel<<<nb_2n, 256, 0, stream>>>(logits, self_logits, rowptr, m_arr, den_arr, N);
    gat_out_kernel<<<nb_wave, 256, 0, stream>>>(bufA, S, rowptr, csr_src, logits, self_logits,
                                                m_arr, den_arr, bg, bufB, S, N);  // B [64] + S
    // dec1: prop@64 then gemm 64->128 (+bd1)
    prop(bufB, bufA, 64, 1.f, 0.f, nullptr, false);
    gemm(7, bufA, T, 1.f, 0.f, bd1, true);
    // dec2: prop@128 then gemm 128->256 (+bd2)
    prop(T, bufB, 128, 1.f, 0.f, nullptr, false);
    gemm(8, bufB, bufA, 1.f, 0.f, bd2, true);
    // dec3: gcn2(A, Wd3) -> A
    prop(bufA, bufB, 256, 1.f - ALPHA_C, ALPHA_C, nullptr, false);
    gemm(9, bufB, bufA, BETA_C, 1.f - BETA_C, nullptr, true);
    // dec4: prop@256 then gemm 256->300 (+bd4)
    prop(bufA, bufB, 256, 1.f, 0.f, nullptr, false);
    gemm(10, bufB, T, 1.f, 0.f, bd4, false);
    // sigmoid in-place on d_out
    sigmoid_kernel<<<(out_size / 4 + 255) / 256, 256, 0, stream>>>(T, (float*)d_out, out_size / 4);
}

// Round 10
// 1274.896 us; speedup vs baseline: 1.7489x; 1.0401x over previous
//
#include <hip/hip_runtime.h>
#include <math.h>

#define NN 50000
#define FIN 300
#define PS 256    // split-plane row stride (u16 per plane)
#define SHS 256   // fp16 shadow row stride
constexpr float ALPHA_C = 0.5f;
constexpr float BETA_C  = 0.09531017980432486f;  // log(1.1)
constexpr float NEG_SLOPE = 0.2f;

typedef unsigned short u16;
typedef __attribute__((ext_vector_type(8))) short short8;
typedef __attribute__((ext_vector_type(4))) float f32x4;
typedef _Float16 hf4 __attribute__((ext_vector_type(4)));

__device__ inline float bfu(u16 u) { return __uint_as_float((unsigned)u << 16); }
__device__ inline u16 bfhi(float x) { return (u16)(__float_as_uint(x) >> 16); }

// ---------------- CSR build ----------------
__global__ void hist_kernel(const int* __restrict__ dst, int* __restrict__ deg, int E) {
    int e = blockIdx.x * blockDim.x + threadIdx.x;
    if (e < E) atomicAdd(&deg[dst[e]], 1);
}

__global__ void scan_kernel(const int* __restrict__ deg, int* __restrict__ rowptr, int n) {
    __shared__ int sh[1024];
    __shared__ int carry;
    if (threadIdx.x == 0) { carry = 0; rowptr[0] = 0; }
    __syncthreads();
    for (int base = 0; base < n; base += 1024) {
        int i = base + threadIdx.x;
        int v = (i < n) ? deg[i] : 0;
        sh[threadIdx.x] = v;
        __syncthreads();
        for (int off = 1; off < 1024; off <<= 1) {
            int t = (threadIdx.x >= off) ? sh[threadIdx.x - off] : 0;
            __syncthreads();
            sh[threadIdx.x] += t;
            __syncthreads();
        }
        if (i < n) rowptr[i + 1] = sh[threadIdx.x] + carry;
        __syncthreads();
        if (threadIdx.x == 0) carry += sh[1023];
        __syncthreads();
    }
}

__global__ void dinv_kernel(const int* __restrict__ deg, float* __restrict__ dinv, int n) {
    int i = blockIdx.x * blockDim.x + threadIdx.x;
    if (i < n) dinv[i] = rsqrtf((float)deg[i] + 1.0f);
}

__global__ void copy_int_kernel(const int* __restrict__ a, int* __restrict__ b, int n) {
    int i = blockIdx.x * blockDim.x + threadIdx.x;
    if (i < n) b[i] = a[i];
}

__global__ void fill_kernel(const int* __restrict__ src, const int* __restrict__ dst,
                            const float* __restrict__ dinv, int* __restrict__ cursor,
                            int* __restrict__ csr_src, float* __restrict__ csr_w, int E) {
    int e = blockIdx.x * blockDim.x + threadIdx.x;
    if (e < E) {
        int s = src[e], d = dst[e];
        int p = atomicAdd(&cursor[d], 1);
        csr_src[p] = s;
        csr_w[p]   = dinv[s] * dinv[d];
    }
}

// ---------------- weight split: W[k][c] -> WhT/WlT [c][k] bf16, zero-padded ----------------
__global__ void splitw_kernel(const float* __restrict__ W, u16* __restrict__ WhT,
                              u16* __restrict__ WlT, int K, int M, int Kp, int total) {
    int t = blockIdx.x * blockDim.x + threadIdx.x;
    if (t >= total) return;
    int c = t / Kp, k = t - c * Kp;
    float x = (c < M && k < K) ? W[(size_t)k * M + c] : 0.f;
    WhT[t] = bfhi(x);
    float lo = x - bfu(bfhi(x));
    WlT[t] = bfhi(lo);
}

// ---------------- gemm0: fp32 A (K=300 tail), 64x64 tile, planes+shadow out ----------------
__global__ __launch_bounds__(256)
void gemm_f32a_kernel(const float* __restrict__ A, const u16* __restrict__ WhT,
                      const u16* __restrict__ WlT, u16* __restrict__ Ch,
                      u16* __restrict__ Cl, _Float16* __restrict__ Cs,
                      int n, int K, int M, int Kp,
                      const float* __restrict__ bias, int gx) {
    __shared__ u16 sAh[64 * 40], sAl[64 * 40], sWh[64 * 40], sWl[64 * 40];
    const int tid = threadIdx.x;
    const int nwg = gridDim.x;
    const int q = nwg >> 3, r = nwg & 7;
    const int xcd = blockIdx.x & 7, off = blockIdx.x >> 3;
    const int wgid = (xcd < r ? xcd * (q + 1) : r * (q + 1) + (xcd - r) * q) + off;
    const int colBase = (wgid % gx) * 64;
    const int rowBase = (wgid / gx) * 64;
    const int lane = tid & 63, wid = tid >> 6;
    const int wr = (wid >> 1) * 32, wc = (wid & 1) * 32;
    const int fr = lane & 15, ko = (lane >> 4) * 8;
    const int wsc = tid >> 2, wsk = (tid & 3) * 8;

    f32x4 acc[2][2] = {};

    for (int k0 = 0; k0 < Kp; k0 += 32) {
        {
            size_t g = (size_t)(colBase + wsc) * Kp + k0 + wsk;
            *(uint4*)&sWh[wsc * 40 + wsk] = *(const uint4*)&WhT[g];
            *(uint4*)&sWl[wsc * 40 + wsk] = *(const uint4*)&WlT[g];
        }
        const bool fullk = (k0 + 32 <= K);
        for (int s = tid; s < 512; s += 256) {
            int rr = s >> 3, kb = (s & 7) * 4;
            int gr = rowBase + rr, kk = k0 + kb;
            float x0 = 0.f, x1 = 0.f, x2 = 0.f, x3 = 0.f;
            if (gr < n) {
                const float* ap = A + (size_t)gr * K + kk;
                if (fullk) { float4 v = *(const float4*)ap; x0 = v.x; x1 = v.y; x2 = v.z; x3 = v.w; }
                else {
                    if (kk     < K) x0 = ap[0];
                    if (kk + 1 < K) x1 = ap[1];
                    if (kk + 2 < K) x2 = ap[2];
                    if (kk + 3 < K) x3 = ap[3];
                }
            }
            unsigned u0 = __float_as_uint(x0), u1 = __float_as_uint(x1);
            unsigned u2 = __float_as_uint(x2), u3 = __float_as_uint(x3);
            uint2 hp; hp.x = (u1 & 0xFFFF0000u) | (u0 >> 16);
                      hp.y = (u3 & 0xFFFF0000u) | (u2 >> 16);
            float l0 = x0 - __uint_as_float(u0 & 0xFFFF0000u);
            float l1 = x1 - __uint_as_float(u1 & 0xFFFF0000u);
            float l2 = x2 - __uint_as_float(u2 & 0xFFFF0000u);
            float l3 = x3 - __uint_as_float(u3 & 0xFFFF0000u);
            uint2 lp; lp.x = (__float_as_uint(l1) & 0xFFFF0000u) | (__float_as_uint(l0) >> 16);
                      lp.y = (__float_as_uint(l3) & 0xFFFF0000u) | (__float_as_uint(l2) >> 16);
            *(uint2*)&sAh[rr * 40 + kb] = hp;
            *(uint2*)&sAl[rr * 40 + kb] = lp;
        }
        __syncthreads();

        short8 ah[2], al[2], bh[2], bl[2];
        ah[0] = *(const short8*)&sAh[(wr +      fr) * 40 + ko];
        ah[1] = *(const short8*)&sAh[(wr + 16 + fr) * 40 + ko];
        al[0] = *(const short8*)&sAl[(wr +      fr) * 40 + ko];
        al[1] = *(const short8*)&sAl[(wr + 16 + fr) * 40 + ko];
        bh[0] = *(const short8*)&sWh[(wc +      fr) * 40 + ko];
        bh[1] = *(const short8*)&sWh[(wc + 16 + fr) * 40 + ko];
        bl[0] = *(const short8*)&sWl[(wc +      fr) * 40 + ko];
        bl[1] = *(const short8*)&sWl[(wc + 16 + fr) * 40 + ko];
#pragma unroll
        for (int i = 0; i < 2; i++)
#pragma unroll
            for (int j = 0; j < 2; j++) {
                acc[i][j] = __builtin_amdgcn_mfma_f32_16x16x32_bf16(al[i], bh[j], acc[i][j], 0, 0, 0);
                acc[i][j] = __builtin_amdgcn_mfma_f32_16x16x32_bf16(ah[i], bl[j], acc[i][j], 0, 0, 0);
                acc[i][j] = __builtin_amdgcn_mfma_f32_16x16x32_bf16(ah[i], bh[j], acc[i][j], 0, 0, 0);
            }
        __syncthreads();
    }

#pragma unroll
    for (int i = 0; i < 2; i++)
#pragma unroll
        for (int j = 0; j < 2; j++) {
            int row0 = rowBase + wr + i * 16 + (lane >> 4) * 4;
            int col  = colBase + wc + j * 16 + fr;
            if (col >= M) continue;
            float bv = bias ? bias[col] : 0.f;
#pragma unroll
            for (int qq = 0; qq < 4; qq++) {
                int rr = row0 + qq;
                if (rr >= n) break;
                float v = acc[i][j][qq] + bv;
                u16 hi = bfhi(v);
                Ch[(size_t)rr * PS + col] = hi;
                Cl[(size_t)rr * PS + col] = bfhi(v - bfu(hi));
                if (Cs) Cs[(size_t)rr * SHS + col] = (_Float16)v;
            }
        }
}

// ---------------- split-plane GEMM: 128x64 tile, copy staging ----------------
// C = cAB*(A@W) + cA*A + bias ; A given as bf16 hi/lo planes [n][PS].
// Outputs: optional fp32 Cf (stride M), optional planes Ch/Cl, optional fp16 Cs.
__global__ __launch_bounds__(256)
void gemm_sp_kernel(const u16* __restrict__ Ah, const u16* __restrict__ Al,
                    const u16* __restrict__ WhT, const u16* __restrict__ WlT,
                    float* __restrict__ Cf, u16* __restrict__ Ch, u16* __restrict__ Cl,
                    _Float16* __restrict__ Cs, int n, int K, int M,
                    float cAB, float cA, const float* __restrict__ bias, int gx) {
    __shared__ u16 sAh[128 * 40], sAl[128 * 40], sWh[64 * 40], sWl[64 * 40];
    const int tid = threadIdx.x;
    const int nwg = gridDim.x;
    const int q = nwg >> 3, r = nwg & 7;
    const int xcd = blockIdx.x & 7, off = blockIdx.x >> 3;
    const int wgid = (xcd < r ? xcd * (q + 1) : r * (q + 1) + (xcd - r) * q) + off;
    const int colBase = (wgid % gx) * 64;
    const int rowBase = (wgid / gx) * 128;
    const int lane = tid & 63, wid = tid >> 6;
    const int wr = wid * 32;                  // wave's 32-row slab
    const int fr = lane & 15, ko = (lane >> 4) * 8;
    const int wsc = tid >> 2, wsk = (tid & 3) * 8;

    f32x4 acc[2][4] = {};

    for (int k0 = 0; k0 < K; k0 += 32) {
        // stage W [64][32] (arena zero-padded rows, K%32==0 -> no guards)
        {
            size_t g = (size_t)(colBase + wsc) * K + k0 + wsk;
            *(uint4*)&sWh[wsc * 40 + wsk] = *(const uint4*)&WhT[g];
            *(uint4*)&sWl[wsc * 40 + wsk] = *(const uint4*)&WlT[g];
        }
        // stage A [128][32]: straight copy of both planes
#pragma unroll
        for (int it = 0; it < 2; ++it) {
            int idx = it * 256 + tid;
            int rr = idx >> 2, qq = (idx & 3) * 8;
            int gr = rowBase + rr;
            uint4 vh = {0, 0, 0, 0}, vl = {0, 0, 0, 0};
            if (gr < n) {
                size_t g = (size_t)gr * PS + k0 + qq;
                vh = *(const uint4*)&Ah[g];
                vl = *(const uint4*)&Al[g];
            }
            *(uint4*)&sAh[rr * 40 + qq] = vh;
            *(uint4*)&sAl[rr * 40 + qq] = vl;
        }
        __syncthreads();

        short8 ah[2], al[2];
        ah[0] = *(const short8*)&sAh[(wr +      fr) * 40 + ko];
        ah[1] = *(const short8*)&sAh[(wr + 16 + fr) * 40 + ko];
        al[0] = *(const short8*)&sAl[(wr +      fr) * 40 + ko];
        al[1] = *(const short8*)&sAl[(wr + 16 + fr) * 40 + ko];
#pragma unroll
        for (int j = 0; j < 4; ++j) {
            short8 bh = *(const short8*)&sWh[(j * 16 + fr) * 40 + ko];
            short8 bl = *(const short8*)&sWl[(j * 16 + fr) * 40 + ko];
#pragma unroll
            for (int i = 0; i < 2; ++i) {
                acc[i][j] = __builtin_amdgcn_mfma_f32_16x16x32_bf16(al[i], bh, acc[i][j], 0, 0, 0);
                acc[i][j] = __builtin_amdgcn_mfma_f32_16x16x32_bf16(ah[i], bl, acc[i][j], 0, 0, 0);
                acc[i][j] = __builtin_amdgcn_mfma_f32_16x16x32_bf16(ah[i], bh, acc[i][j], 0, 0, 0);
            }
        }
        __syncthreads();
    }

    // epilogue: C/D layout col=lane&15, row=(lane>>4)*4+q  [m89-verified]
#pragma unroll
    for (int i = 0; i < 2; i++)
#pragma unroll
        for (int j = 0; j < 4; j++) {
            int row0 = rowBase + wr + i * 16 + (lane >> 4) * 4;
            int col  = colBase + j * 16 + fr;
            if (col >= M) continue;
            float bv = bias ? bias[col] : 0.f;
#pragma unroll
            for (int qq = 0; qq < 4; qq++) {
                int rr = row0 + qq;
                if (rr >= n) break;
                float v = cAB * acc[i][j][qq] + bv;
                if (cA != 0.f)   // GCN2: M==K, reconstruct A from planes
                    v += cA * (bfu(Ah[(size_t)rr * PS + col]) + bfu(Al[(size_t)rr * PS + col]));
                if (Cf) Cf[(size_t)rr * M + col] = v;
                if (Ch) {
                    u16 hi = bfhi(v);
                    Ch[(size_t)rr * PS + col] = hi;
                    Cl[(size_t)rr * PS + col] = bfhi(v - bfu(hi));
                }
                if (Cs) Cs[(size_t)rr * SHS + col] = (_Float16)v;
            }
        }
}

// ---- prop: self from planes, gather from fp16 shadow; writes planes (+shadow) ----
__global__ __launch_bounds__(256)
void prop_kernel(const u16* __restrict__ Ah, const u16* __restrict__ Al,
                 const _Float16* __restrict__ hs,
                 u16* __restrict__ Oh, u16* __restrict__ Ol, _Float16* __restrict__ outs,
                 const int* __restrict__ rowptr, const int* __restrict__ csr_src,
                 const float* __restrict__ csr_w, const float* __restrict__ dinv,
                 const float* __restrict__ bias, int n, int D, float cP, float cH) {
    int wv = (blockIdx.x * blockDim.x + threadIdx.x) >> 6;
    int lane = threadIdx.x & 63;
    int D4 = D >> 2;
    int npw = 64 / D4;
    int sub = lane / D4;
    int cl = lane - sub * D4;
    int i = wv * npw + sub;
    if (i >= n) return;
    int c = cl * 4;
    ushort4 th = *(const ushort4*)&Ah[(size_t)i * PS + c];
    ushort4 tl = *(const ushort4*)&Al[(size_t)i * PS + c];
    float4 hv = {bfu(th.x) + bfu(tl.x), bfu(th.y) + bfu(tl.y),
                 bfu(th.z) + bfu(tl.z), bfu(th.w) + bfu(tl.w)};
    float sw = dinv[i] * dinv[i];
    float4 a0 = {sw * hv.x, sw * hv.y, sw * hv.z, sw * hv.w};
    float4 a1 = {0,0,0,0}, a2 = {0,0,0,0}, a3 = {0,0,0,0};
    int p0 = rowptr[i], p1 = rowptr[i + 1];
    int p = p0;
    for (; p + 4 <= p1; p += 4) {
        int s0 = csr_src[p], s1 = csr_src[p+1], s2 = csr_src[p+2], s3 = csr_src[p+3];
        float w0 = csr_w[p], w1 = csr_w[p+1], w2 = csr_w[p+2], w3 = csr_w[p+3];
        hf4 v0 = *(const hf4*)&hs[(size_t)s0 * SHS + c];
        hf4 v1 = *(const hf4*)&hs[(size_t)s1 * SHS + c];
        hf4 v2 = *(const hf4*)&hs[(size_t)s2 * SHS + c];
        hf4 v3 = *(const hf4*)&hs[(size_t)s3 * SHS + c];
        a0.x += w0*(float)v0[0]; a0.y += w0*(float)v0[1]; a0.z += w0*(float)v0[2]; a0.w += w0*(float)v0[3];
        a1.x += w1*(float)v1[0]; a1.y += w1*(float)v1[1]; a1.z += w1*(float)v1[2]; a1.w += w1*(float)v1[3];
        a2.x += w2*(float)v2[0]; a2.y += w2*(float)v2[1]; a2.z += w2*(float)v2[2]; a2.w += w2*(float)v2[3];
        a3.x += w3*(float)v3[0]; a3.y += w3*(float)v3[1]; a3.z += w3*(float)v3[2]; a3.w += w3*(float)v3[3];
    }
    for (; p < p1; ++p) {
        int s = csr_src[p];
        float w = csr_w[p];
        hf4 v = *(const hf4*)&hs[(size_t)s * SHS + c];
        a0.x += w*(float)v[0]; a0.y += w*(float)v[1]; a0.z += w*(float)v[2]; a0.w += w*(float)v[3];
    }
    float4 acc = {a0.x + a1.x + a2.x + a3.x, a0.y + a1.y + a2.y + a3.y,
                  a0.z + a1.z + a2.z + a3.z, a0.w + a1.w + a2.w + a3.w};
    float4 rr = {cP * acc.x, cP * acc.y, cP * acc.z, cP * acc.w};
    if (cH != 0.f) { rr.x += cH * hv.x; rr.y += cH * hv.y; rr.z += cH * hv.z; rr.w += cH * hv.w; }
    if (bias) { float4 b = ((const float4*)bias)[cl]; rr.x += b.x; rr.y += b.y; rr.z += b.z; rr.w += b.w; }
    ushort4 oh, ol;
    oh.x = bfhi(rr.x); ol.x = bfhi(rr.x - bfu(oh.x));
    oh.y = bfhi(rr.y); ol.y = bfhi(rr.y - bfu(oh.y));
    oh.z = bfhi(rr.z); ol.z = bfhi(rr.z - bfu(oh.z));
    oh.w = bfhi(rr.w); ol.w = bfhi(rr.w - bfu(oh.w));
    *(ushort4*)&Oh[(size_t)i * PS + c] = oh;
    *(ushort4*)&Ol[(size_t)i * PS + c] = ol;
    if (outs) {
        hf4 o; o[0] = (_Float16)rr.x; o[1] = (_Float16)rr.y; o[2] = (_Float16)rr.z; o[3] = (_Float16)rr.w;
        *(hf4*)&outs[(size_t)i * SHS + c] = o;
    }
}

// ---------------- GATv2 ----------------
__device__ inline float lrelu(float x) { return x > 0.f ? x : NEG_SLOPE * x; }

__global__ __launch_bounds__(256)
void gat_logits_kernel(const u16* __restrict__ xlh, const u16* __restrict__ xll,
                       const _Float16* __restrict__ xls,
                       const float* __restrict__ xr, const float* __restrict__ att,
                       const int* __restrict__ rowptr, const int* __restrict__ csr_src,
                       float* __restrict__ logits, float* __restrict__ self_logits, int n) {
    int t = blockIdx.x * blockDim.x + threadIdx.x;
    int i = t >> 1, hh = t & 1;
    if (i >= n) return;
    float4 attv[8], xrv[8];
    const float4* att4 = (const float4*)att;
    const float4* xr4 = (const float4*)xr;
#pragma unroll
    for (int c = 0; c < 8; c++) {
        attv[c] = att4[hh * 8 + c];
        xrv[c]  = xr4[(long)i * 16 + hh * 8 + c];
    }
    // self edge: xl from planes
    {
        float s = 0.f;
        size_t b = (size_t)i * PS + hh * 32;
#pragma unroll
        for (int c = 0; c < 8; c++) {
            ushort4 eh = *(const ushort4*)&xlh[b + c * 4];
            ushort4 el = *(const ushort4*)&xll[b + c * 4];
            s += lrelu(bfu(eh.x) + bfu(el.x) + xrv[c].x) * attv[c].x;
            s += lrelu(bfu(eh.y) + bfu(el.y) + xrv[c].y) * attv[c].y;
            s += lrelu(bfu(eh.z) + bfu(el.z) + xrv[c].z) * attv[c].z;
            s += lrelu(bfu(eh.w) + bfu(el.w) + xrv[c].w) * attv[c].w;
        }
        self_logits[i * 2 + hh] = s;
    }
    int p0 = rowptr[i], p1 = rowptr[i + 1];
    for (int p = p0; p < p1; ++p) {
        int sn = csr_src[p];
        size_t b = (size_t)sn * SHS + hh * 32;
        float s = 0.f;
#pragma unroll
        for (int c = 0; c < 8; c++) {
            hf4 e = *(const hf4*)&xls[b + c * 4];
            s += lrelu((float)e[0] + xrv[c].x) * attv[c].x;
            s += lrelu((float)e[1] + xrv[c].y) * attv[c].y;
            s += lrelu((float)e[2] + xrv[c].z) * attv[c].z;
            s += lrelu((float)e[3] + xrv[c].w) * attv[c].w;
        }
        logits[(long)p * 2 + hh] = s;
    }
}

__global__ __launch_bounds__(256)
void gat_mden_kernel(const float* __restrict__ logits, const float* __restrict__ self_logits,
                     const int* __restrict__ rowptr, float* __restrict__ m_arr,
                     float* __restrict__ den_arr, int n) {
    int t = blockIdx.x * blockDim.x + threadIdx.x;
    int i = t >> 1, hh = t & 1;
    if (i >= n) return;
    int p0 = rowptr[i], p1 = rowptr[i + 1];
    float m = self_logits[i * 2 + hh];
    for (int p = p0; p < p1; ++p) m = fmaxf(m, logits[(long)p * 2 + hh]);
    float den = expf(self_logits[i * 2 + hh] - m);
    for (int p = p0; p < p1; ++p) den += expf(logits[(long)p * 2 + hh] - m);
    m_arr[i * 2 + hh] = m;
    den_arr[i * 2 + hh] = den;
}

__global__ __launch_bounds__(256)
void gat_out_kernel(const u16* __restrict__ xlh, const u16* __restrict__ xll,
                    const _Float16* __restrict__ xls,
                    const int* __restrict__ rowptr, const int* __restrict__ csr_src,
                    const float* __restrict__ logits, const float* __restrict__ self_logits,
                    const float* __restrict__ m_arr, const float* __restrict__ den_arr,
                    const float* __restrict__ bias, u16* __restrict__ Oh,
                    u16* __restrict__ Ol, _Float16* __restrict__ outs, int n) {
    int i = (blockIdx.x * blockDim.x + threadIdx.x) >> 6;
    int lane = threadIdx.x & 63;
    if (i >= n) return;
    int hh = lane >> 5;
    float m = m_arr[i * 2 + hh];
    float inv = 1.f / (den_arr[i * 2 + hh] + 1e-16f);
    float xv = bfu(xlh[(size_t)i * PS + lane]) + bfu(xll[(size_t)i * PS + lane]);
    float acc = expf(self_logits[i * 2 + hh] - m) * inv * xv;
    int p0 = rowptr[i], p1 = rowptr[i + 1];
    for (int p = p0; p < p1; ++p) {
        float w = expf(logits[(long)p * 2 + hh] - m) * inv;
        acc += w * (float)xls[(size_t)csr_src[p] * SHS + lane];
    }
    float r = fmaxf(acc + bias[lane], 0.f);   // bias + ReLU fused
    u16 hi = bfhi(r);
    Oh[(size_t)i * PS + lane] = hi;
    Ol[(size_t)i * PS + lane] = bfhi(r - bfu(hi));
    outs[(size_t)i * SHS + lane] = (_Float16)r;
}

__global__ void sigmoid_kernel(const float* __restrict__ in, float* __restrict__ out, int n4) {
    int i = blockIdx.x * blockDim.x + threadIdx.x;
    if (i < n4) {
        float4 v = ((const float4*)in)[i];
        float4 r;
        r.x = 1.f / (1.f + expf(-v.x));
        r.y = 1.f / (1.f + expf(-v.y));
        r.z = 1.f / (1.f + expf(-v.z));
        r.w = 1.f / (1.f + expf(-v.w));
        ((float4*)out)[i] = r;
    }
}

// ---------------- launch ----------------
extern "C" void kernel_launch(void* const* d_in, const int* in_sizes, int n_in,
                              void* d_out, int out_size, void* d_ws, size_t ws_size,
                              hipStream_t stream) {
    const int N = NN;
    const int E = in_sizes[1] / 2;

    struct WSpec { int idx; int K, M; };
    const WSpec wspec[11] = {
        {2, 300, 256},   // W1
        {4, 256, 256},   // W2
        {5, 256, 128},   // W3
        {7, 128, 64},    // W4
        {9, 64, 32},     // W5
        {11, 32, 64},    // Wl
        {12, 32, 64},    // Wr
        {15, 64, 128},   // Wd1
        {17, 128, 256},  // Wd2
        {19, 256, 256},  // Wd3
        {20, 256, 300},  // Wd4
    };
    size_t arena_elems = 0;
    int kp[11], mp[11];
    size_t woff[11];
    for (int i = 0; i < 11; i++) {
        kp[i] = (wspec[i].K + 31) & ~31;
        mp[i] = (wspec[i].M + 63) & ~63;
        woff[i] = arena_elems;
        arena_elems += (size_t)2 * mp[i] * kp[i];
    }

    size_t need = 0;
    need += (size_t)N * PS * 2 * 4;      // 4 planes (PA h/l, PB h/l)
    need += (size_t)N * SHS * 2 * 2;     // 2 fp16 shadows
    need += (size_t)E * 4;               // csr_w
    need += (size_t)E * 2 * 4;           // logits
    need += (size_t)N * 2 * 4 * 3;       // self_logits, m_arr, den_arr
    need += (size_t)N * 4 * 3;           // dinv, deg, cursor
    need += (size_t)(N + 4) * 4;         // rowptr
    need += (size_t)E * 4;               // csr_src
    need += arena_elems * 2 + 128;       // bf16 weight arena + align slack
    if (ws_size < need) return;

    const float* x      = (const float*)d_in[0];
    const int*   ei     = (const int*)d_in[1];
    const int*   e_src  = ei;
    const int*   e_dst  = ei + E;
    const float* b1  = (const float*)d_in[3];
    const float* b3  = (const float*)d_in[6];
    const float* b4  = (const float*)d_in[8];
    const float* b5  = (const float*)d_in[10];
    const float* attw= (const float*)d_in[13];
    const float* bg  = (const float*)d_in[14];
    const float* bd1 = (const float*)d_in[16];
    const float* bd2 = (const float*)d_in[18];
    const float* bd4 = (const float*)d_in[21];

    char* w = (char*)d_ws;
    u16* PAh = (u16*)w;                      w += (size_t)N * PS * 2;
    u16* PAl = (u16*)w;                      w += (size_t)N * PS * 2;
    u16* PBh = (u16*)w;                      w += (size_t)N * PS * 2;
    u16* PBl = (u16*)w;                      w += (size_t)N * PS * 2;
    _Float16* S0 = (_Float16*)w;             w += (size_t)N * SHS * 2;
    _Float16* S1 = (_Float16*)w;             w += (size_t)N * SHS * 2;
    float* csr_w = (float*)w;                w += (size_t)E * 4;
    float* logits = (float*)w;               w += (size_t)E * 2 * 4;
    float* self_logits = (float*)w;          w += (size_t)N * 2 * 4;
    float* m_arr = (float*)w;                w += (size_t)N * 2 * 4;
    float* den_arr = (float*)w;              w += (size_t)N * 2 * 4;
    float* dinv = (float*)w;                 w += (size_t)N * 4;
    int* deg = (int*)w;                      w += (size_t)N * 4;
    int* rowptr = (int*)w;                   w += (size_t)(N + 4) * 4;
    int* cursor = (int*)w;                   w += (size_t)N * 4;
    int* csr_src = (int*)w;                  w += (size_t)E * 4;
    w = (char*)(((size_t)w + 63) & ~(size_t)63);
    u16* arena = (u16*)w;                    w += arena_elems * 2;
    float* T = (float*)d_out;                // fp32 tmp (xr [N][64]; final [N][300])

    int nb_e = (E + 255) / 256;
    int nb_n = (N + 255) / 256;
    int nb_wave = (N + 3) / 4;
    int nb_2n = (2 * N + 255) / 256;

    for (int i = 0; i < 11; i++) {
        int total = mp[i] * kp[i];
        splitw_kernel<<<(total + 255) / 256, 256, 0, stream>>>(
            (const float*)d_in[wspec[i].idx], arena + woff[i], arena + woff[i] + total,
            wspec[i].K, wspec[i].M, kp[i], total);
    }

    hipMemsetAsync(deg, 0, (size_t)N * 4, stream);
    hist_kernel<<<nb_e, 256, 0, stream>>>(e_dst, deg, E);
    scan_kernel<<<1, 1024, 0, stream>>>(deg, rowptr, N);
    dinv_kernel<<<nb_n, 256, 0, stream>>>(deg, dinv, N);
    copy_int_kernel<<<nb_n, 256, 0, stream>>>(rowptr, cursor, N);
    fill_kernel<<<nb_e, 256, 0, stream>>>(e_src, e_dst, dinv, cursor, csr_src, csr_w, E);

    // split-plane gemm
    auto gemm = [&](int wi, const u16* Ah, const u16* Al, float* Cf, u16* Ch, u16* Cl,
                    _Float16* Cs, float cAB, float cA, const float* bias) {
        int K = wspec[wi].K, M = wspec[wi].M;
        int total = mp[wi] * kp[wi];
        int gx = (M + 63) / 64, gy = (N + 127) / 128;
        gemm_sp_kernel<<<gx * gy, 256, 0, stream>>>(
            Ah, Al, arena + woff[wi], arena + woff[wi] + total,
            Cf, Ch, Cl, Cs, N, K, M, cAB, cA, bias, gx);
    };
    auto prop = [&](const u16* Ah, const u16* Al, const _Float16* hs,
                    u16* Oh, u16* Ol, _Float16* outs, int D, float cP, float cH,
                    const float* bias) {
        int npw = 64 / (D >> 2);
        int npb = 4 * npw;
        int nb = (N + npb - 1) / npb;
        prop_kernel<<<nb, 256, 0, stream>>>(Ah, Al, hs, Oh, Ol, outs,
                                            rowptr, csr_src, csr_w, dinv,
                                            bias, N, D, cP, cH);
    };

    // 1. gemm0: x -> PA + S0  (fp32-A path, K=300)
    {
        int gx = (256 + 63) / 64, gy = (N + 63) / 64;
        gemm_f32a_kernel<<<gx * gy, 256, 0, stream>>>(
            x, arena + woff[0], arena + woff[0] + mp[0] * kp[0],
            PAh, PAl, S0, N, 300, 256, kp[0], nullptr, gx);
    }
    // 2. prop L1: self PA, gather S0 -> PB + S1  (bias b1)
    prop(PAh, PAl, S0, PBh, PBl, S1, 256, 1.f, 0.f, b1);
    // 3. prop L2 (GCN2 hp): self PB, gather S1 -> PA
    prop(PBh, PBl, S1, PAh, PAl, nullptr, 256, 1.f - ALPHA_C, ALPHA_C, nullptr);
    // 4. gemm1: A=PA -> PB   (beta*hp@W2 + (1-beta)*hp)
    gemm(1, PAh, PAl, nullptr, PBh, PBl, nullptr, BETA_C, 1.f - BETA_C, nullptr);
    // 5. gemm2: A=PB -> PA + S0  [128]
    gemm(2, PBh, PBl, nullptr, PAh, PAl, S0, 1.f, 0.f, nullptr);
    // 6. prop L3: self PA, gather S0 -> PB  (bias b3)
    prop(PAh, PAl, S0, PBh, PBl, nullptr, 128, 1.f, 0.f, b3);
    // 7. gemm3: A=PB -> PA + S1  [64]
    gemm(3, PBh, PBl, nullptr, PAh, PAl, S1, 1.f, 0.f, nullptr);
    // 8. prop L4: self PA, gather S1 -> PB  (bias b4)
    prop(PAh, PAl, S1, PBh, PBl, nullptr, 64, 1.f, 0.f, b4);
    // 9. gemm4: A=PB -> PA + S0  [32]
    gemm(4, PBh, PBl, nullptr, PAh, PAl, S0, 1.f, 0.f, nullptr);
    // 10. prop L5: self PA, gather S0 -> PB  (bias b5)
    prop(PAh, PAl, S0, PBh, PBl, nullptr, 32, 1.f, 0.f, b5);
    // 11. gemm5 (xl): A=PB -> PA + S1
    gemm(5, PBh, PBl, nullptr, PAh, PAl, S1, 1.f, 0.f, nullptr);
    // 12. gemm6 (xr): A=PB -> T fp32 [N][64]
    gemm(6, PBh, PBl, T, nullptr, nullptr, nullptr, 1.f, 0.f, nullptr);
    // 13-15. GAT
    gat_logits_kernel<<<nb_2n, 256, 0, stream>>>(PAh, PAl, S1, T, attw, rowptr, csr_src,
                                                 logits, self_logits, N);
    gat_mden_kernel<<<nb_2n, 256, 0, stream>>>(logits, self_logits, rowptr, m_arr, den_arr, N);
    gat_out_kernel<<<nb_wave, 256, 0, stream>>>(PAh, PAl, S1, rowptr, csr_src, logits,
                                                self_logits, m_arr, den_arr, bg,
                                                PBh, PBl, S0, N);   // -> PB + S0 (ReLU)
    // 16. prop dec1: self PB, gather S0 -> PA  [64]
    prop(PBh, PBl, S0, PAh, PAl, nullptr, 64, 1.f, 0.f, nullptr);
    // 17. gemm7: A=PA -> PB + S1  [128] (bias bd1)
    gemm(7, PAh, PAl, nullptr, PBh, PBl, S1, 1.f, 0.f, bd1);
    // 18. prop dec2: self PB, gather S1 -> PA  [128]
    prop(PBh, PBl, S1, PAh, PAl, nullptr, 128, 1.f, 0.f, nullptr);
    // 19. gemm8: A=PA -> PB + S0  [256] (bias bd2)
    gemm(8, PAh, PAl, nullptr, PBh, PBl, S0, 1.f, 0.f, bd2);
    // 20. prop dec3 (GCN2 hp): self PB, gather S0 -> PA
    prop(PBh, PBl, S0, PAh, PAl, nullptr, 256, 1.f - ALPHA_C, ALPHA_C, nullptr);
    // 21. gemm9: A=PA -> PB + S1
    gemm(9, PAh, PAl, nullptr, PBh, PBl, S1, BETA_C, 1.f - BETA_C, nullptr);
    // 22. prop dec4: self PB, gather S1 -> PA
    prop(PBh, PBl, S1, PAh, PAl, nullptr, 256, 1.f, 0.f, nullptr);
    // 23. gemm10: A=PA -> T fp32 [300] (bias bd4)
    gemm(10, PAh, PAl, T, nullptr, nullptr, nullptr, 1.f, 0.f, bd4);
    // 24. sigmoid in-place on d_out
    sigmoid_kernel<<<(out_size / 4 + 255) / 256, 256, 0, stream>>>(T, (float*)d_out, out_size / 4);
}

// Round 11
// 1088.732 us; speedup vs baseline: 2.0480x; 1.1710x over previous
//
#include <hip/hip_runtime.h>
#include <math.h>

#define NN 50000
#define FIN 300
#define SHS 256   // fp16 activation row stride
#define XS  320   // fp16 input-copy row stride (300 padded to 32)
constexpr float ALPHA_C = 0.5f;
constexpr float BETA_C  = 0.09531017980432486f;  // log(1.1)
constexpr float NEG_SLOPE = 0.2f;

typedef unsigned short u16;
typedef __attribute__((ext_vector_type(4))) float f32x4;
typedef _Float16 hf4 __attribute__((ext_vector_type(4)));
typedef _Float16 half8 __attribute__((ext_vector_type(8)));

// ---------------- CSR build ----------------
__global__ void hist_kernel(const int* __restrict__ dst, int* __restrict__ deg, int E) {
    int e = blockIdx.x * blockDim.x + threadIdx.x;
    if (e < E) atomicAdd(&deg[dst[e]], 1);
}

__global__ void scan_kernel(const int* __restrict__ deg, int* __restrict__ rowptr, int n) {
    __shared__ int sh[1024];
    __shared__ int carry;
    if (threadIdx.x == 0) { carry = 0; rowptr[0] = 0; }
    __syncthreads();
    for (int base = 0; base < n; base += 1024) {
        int i = base + threadIdx.x;
        int v = (i < n) ? deg[i] : 0;
        sh[threadIdx.x] = v;
        __syncthreads();
        for (int off = 1; off < 1024; off <<= 1) {
            int t = (threadIdx.x >= off) ? sh[threadIdx.x - off] : 0;
            __syncthreads();
            sh[threadIdx.x] += t;
            __syncthreads();
        }
        if (i < n) rowptr[i + 1] = sh[threadIdx.x] + carry;
        __syncthreads();
        if (threadIdx.x == 0) carry += sh[1023];
        __syncthreads();
    }
}

__global__ void dinv_kernel(const int* __restrict__ deg, float* __restrict__ dinv, int n) {
    int i = blockIdx.x * blockDim.x + threadIdx.x;
    if (i < n) dinv[i] = rsqrtf((float)deg[i] + 1.0f);
}

__global__ void copy_int_kernel(const int* __restrict__ a, int* __restrict__ b, int n) {
    int i = blockIdx.x * blockDim.x + threadIdx.x;
    if (i < n) b[i] = a[i];
}

__global__ void fill_kernel(const int* __restrict__ src, const int* __restrict__ dst,
                            const float* __restrict__ dinv, int* __restrict__ cursor,
                            int* __restrict__ csr_src, float* __restrict__ csr_w, int E) {
    int e = blockIdx.x * blockDim.x + threadIdx.x;
    if (e < E) {
        int s = src[e], d = dst[e];
        int p = atomicAdd(&cursor[d], 1);
        csr_src[p] = s;
        csr_w[p]   = dinv[s] * dinv[d];
    }
}

// ---------------- x fp32 -> fp16, [N][300] -> [N][XS] zero-padded ----------------
__global__ void cvt_x_kernel(const float* __restrict__ x, _Float16* __restrict__ FX, int total) {
    int t = blockIdx.x * blockDim.x + threadIdx.x;
    if (t >= total) return;
    int i = t / XS, c = t - i * XS;
    FX[t] = (c < FIN) ? (_Float16)x[(size_t)i * FIN + c] : (_Float16)0.f;
}

// ---------------- weight split: W[k][c] -> f16 WhT/WlT [c][k], zero-padded ----------------
__global__ void splitw_kernel(const float* __restrict__ W, _Float16* __restrict__ WhT,
                              _Float16* __restrict__ WlT, int K, int M, int Kp, int total) {
    int t = blockIdx.x * blockDim.x + threadIdx.x;
    if (t >= total) return;
    int c = t / Kp, k = t - c * Kp;
    float x = (c < M && k < K) ? W[(size_t)k * M + c] : 0.f;
    _Float16 hi = (_Float16)x;
    WhT[t] = hi;
    WlT[t] = (_Float16)(x - (float)hi);
}

// ---------------- f16 MFMA GEMM (64x64 tile, XCD swizzle) ----------------
// C = cAB*(A@W) + cA*A + bias; A fp16 [n][lda]; W = f16 hi/lo [Mp][Kl] (zero-padded).
// Weights-only Markidis: A*Wh + A*Wl, fp32 accumulate.
__global__ __launch_bounds__(256)
void gemm_f16_kernel(const _Float16* __restrict__ A, int lda,
                     const _Float16* __restrict__ WhT, const _Float16* __restrict__ WlT,
                     float* __restrict__ Cf, _Float16* __restrict__ Co,
                     int n, int Kl, int M,
                     float cAB, float cA, const float* __restrict__ bias, int gx) {
    __shared__ _Float16 sA[64 * 40], sWh[64 * 40], sWl[64 * 40];
    const int tid = threadIdx.x;
    // m204 bijective XCD swizzle; col fastest -> A-panel-sharing blocks same XCD
    const int nwg = gridDim.x;
    const int q = nwg >> 3, r = nwg & 7;
    const int xcd = blockIdx.x & 7, off = blockIdx.x >> 3;
    const int wgid = (xcd < r ? xcd * (q + 1) : r * (q + 1) + (xcd - r) * q) + off;
    const int colBase = (wgid % gx) * 64;
    const int rowBase = (wgid / gx) * 64;
    const int lane = tid & 63, wid = tid >> 6;
    const int wr = (wid >> 1) * 32, wc = (wid & 1) * 32;
    const int fr = lane & 15, ko = (lane >> 4) * 8;
    const int wsc = tid >> 2, wsk = (tid & 3) * 8;
    const int arr = tid >> 2, akq = (tid & 3) * 8;   // A staging coords

    f32x4 acc[2][2] = {};

    for (int k0 = 0; k0 < Kl; k0 += 32) {
        // stage W [64][32] hi+lo (arena zero-padded, no guards)
        {
            size_t g = (size_t)(colBase + wsc) * Kl + k0 + wsk;
            *(uint4*)&sWh[wsc * 40 + wsk] = *(const uint4*)&WhT[g];
            *(uint4*)&sWl[wsc * 40 + wsk] = *(const uint4*)&WlT[g];
        }
        // stage A [64][32]: straight fp16 copy
        {
            int gr = rowBase + arr;
            uint4 v = {0, 0, 0, 0};
            if (gr < n) v = *(const uint4*)&A[(size_t)gr * lda + k0 + akq];
            *(uint4*)&sA[arr * 40 + akq] = v;
        }
        __syncthreads();

        half8 av[2], bh[2], bl[2];
        av[0] = *(const half8*)&sA[(wr +      fr) * 40 + ko];
        av[1] = *(const half8*)&sA[(wr + 16 + fr) * 40 + ko];
        bh[0] = *(const half8*)&sWh[(wc +      fr) * 40 + ko];
        bh[1] = *(const half8*)&sWh[(wc + 16 + fr) * 40 + ko];
        bl[0] = *(const half8*)&sWl[(wc +      fr) * 40 + ko];
        bl[1] = *(const half8*)&sWl[(wc + 16 + fr) * 40 + ko];
#pragma unroll
        for (int i = 0; i < 2; i++)
#pragma unroll
            for (int j = 0; j < 2; j++) {
                acc[i][j] = __builtin_amdgcn_mfma_f32_16x16x32_f16(av[i], bl[j], acc[i][j], 0, 0, 0);
                acc[i][j] = __builtin_amdgcn_mfma_f32_16x16x32_f16(av[i], bh[j], acc[i][j], 0, 0, 0);
            }
        __syncthreads();
    }

    // epilogue: C/D layout col=lane&15, row=(lane>>4)*4+q  [m89-verified]
#pragma unroll
    for (int i = 0; i < 2; i++)
#pragma unroll
        for (int j = 0; j < 2; j++) {
            int row0 = rowBase + wr + i * 16 + (lane >> 4) * 4;
            int col  = colBase + wc + j * 16 + fr;
            if (col >= M) continue;
            float bv = bias ? bias[col] : 0.f;
#pragma unroll
            for (int qq = 0; qq < 4; qq++) {
                int rr = row0 + qq;
                if (rr >= n) break;
                float v = cAB * acc[i][j][qq] + bv;
                if (cA != 0.f) v += cA * (float)A[(size_t)rr * lda + col];  // GCN2: M==K
                if (Cf) Cf[(size_t)rr * M + col] = v;
                if (Co) Co[(size_t)rr * SHS + col] = (_Float16)v;
            }
        }
}

// ---- prop: out = cP*(D^-1/2 A D^-1/2 h) + cH*h + bias ; all fp16 in/out ----
__global__ __launch_bounds__(256)
void prop_kernel(const _Float16* __restrict__ Fin, _Float16* __restrict__ Fout,
                 const int* __restrict__ rowptr, const int* __restrict__ csr_src,
                 const float* __restrict__ csr_w, const float* __restrict__ dinv,
                 const float* __restrict__ bias, int n, int D, float cP, float cH) {
    int wv = (blockIdx.x * blockDim.x + threadIdx.x) >> 6;
    int lane = threadIdx.x & 63;
    int D4 = D >> 2;
    int npw = 64 / D4;
    int sub = lane / D4;
    int cl = lane - sub * D4;
    int i = wv * npw + sub;
    if (i >= n) return;
    int c = cl * 4;
    hf4 th = *(const hf4*)&Fin[(size_t)i * SHS + c];
    float4 hv = {(float)th[0], (float)th[1], (float)th[2], (float)th[3]};
    float sw = dinv[i] * dinv[i];
    float4 a0 = {sw * hv.x, sw * hv.y, sw * hv.z, sw * hv.w};
    float4 a1 = {0,0,0,0}, a2 = {0,0,0,0}, a3 = {0,0,0,0};
    int p0 = rowptr[i], p1 = rowptr[i + 1];
    int p = p0;
    for (; p + 4 <= p1; p += 4) {
        int s0 = csr_src[p], s1 = csr_src[p+1], s2 = csr_src[p+2], s3 = csr_src[p+3];
        float w0 = csr_w[p], w1 = csr_w[p+1], w2 = csr_w[p+2], w3 = csr_w[p+3];
        hf4 v0 = *(const hf4*)&Fin[(size_t)s0 * SHS + c];
        hf4 v1 = *(const hf4*)&Fin[(size_t)s1 * SHS + c];
        hf4 v2 = *(const hf4*)&Fin[(size_t)s2 * SHS + c];
        hf4 v3 = *(const hf4*)&Fin[(size_t)s3 * SHS + c];
        a0.x += w0*(float)v0[0]; a0.y += w0*(float)v0[1]; a0.z += w0*(float)v0[2]; a0.w += w0*(float)v0[3];
        a1.x += w1*(float)v1[0]; a1.y += w1*(float)v1[1]; a1.z += w1*(float)v1[2]; a1.w += w1*(float)v1[3];
        a2.x += w2*(float)v2[0]; a2.y += w2*(float)v2[1]; a2.z += w2*(float)v2[2]; a2.w += w2*(float)v2[3];
        a3.x += w3*(float)v3[0]; a3.y += w3*(float)v3[1]; a3.z += w3*(float)v3[2]; a3.w += w3*(float)v3[3];
    }
    for (; p < p1; ++p) {
        int s = csr_src[p];
        float w = csr_w[p];
        hf4 v = *(const hf4*)&Fin[(size_t)s * SHS + c];
        a0.x += w*(float)v[0]; a0.y += w*(float)v[1]; a0.z += w*(float)v[2]; a0.w += w*(float)v[3];
    }
    float4 acc = {a0.x + a1.x + a2.x + a3.x, a0.y + a1.y + a2.y + a3.y,
                  a0.z + a1.z + a2.z + a3.z, a0.w + a1.w + a2.w + a3.w};
    float4 rr = {cP * acc.x, cP * acc.y, cP * acc.z, cP * acc.w};
    if (cH != 0.f) { rr.x += cH * hv.x; rr.y += cH * hv.y; rr.z += cH * hv.z; rr.w += cH * hv.w; }
    if (bias) { float4 b = ((const float4*)bias)[cl]; rr.x += b.x; rr.y += b.y; rr.z += b.z; rr.w += b.w; }
    hf4 o; o[0] = (_Float16)rr.x; o[1] = (_Float16)rr.y; o[2] = (_Float16)rr.z; o[3] = (_Float16)rr.w;
    *(hf4*)&Fout[(size_t)i * SHS + c] = o;
}

// ---------------- GATv2 ----------------
__device__ inline float lrelu(float x) { return x > 0.f ? x : NEG_SLOPE * x; }

__global__ __launch_bounds__(256)
void gat_logits_kernel(const _Float16* __restrict__ xl, const float* __restrict__ xr,
                       const float* __restrict__ att, const int* __restrict__ rowptr,
                       const int* __restrict__ csr_src, float* __restrict__ logits,
                       float* __restrict__ self_logits, int n) {
    int t = blockIdx.x * blockDim.x + threadIdx.x;
    int i = t >> 1, hh = t & 1;
    if (i >= n) return;
    float4 attv[8], xrv[8];
    const float4* att4 = (const float4*)att;
    const float4* xr4 = (const float4*)xr;
#pragma unroll
    for (int c = 0; c < 8; c++) {
        attv[c] = att4[hh * 8 + c];
        xrv[c]  = xr4[(long)i * 16 + hh * 8 + c];
    }
    {
        float s = 0.f;
        size_t b = (size_t)i * SHS + hh * 32;
#pragma unroll
        for (int c = 0; c < 8; c++) {
            hf4 e = *(const hf4*)&xl[b + c * 4];
            s += lrelu((float)e[0] + xrv[c].x) * attv[c].x;
            s += lrelu((float)e[1] + xrv[c].y) * attv[c].y;
            s += lrelu((float)e[2] + xrv[c].z) * attv[c].z;
            s += lrelu((float)e[3] + xrv[c].w) * attv[c].w;
        }
        self_logits[i * 2 + hh] = s;
    }
    int p0 = rowptr[i], p1 = rowptr[i + 1];
    for (int p = p0; p < p1; ++p) {
        int sn = csr_src[p];
        size_t b = (size_t)sn * SHS + hh * 32;
        float s = 0.f;
#pragma unroll
        for (int c = 0; c < 8; c++) {
            hf4 e = *(const hf4*)&xl[b + c * 4];
            s += lrelu((float)e[0] + xrv[c].x) * attv[c].x;
            s += lrelu((float)e[1] + xrv[c].y) * attv[c].y;
            s += lrelu((float)e[2] + xrv[c].z) * attv[c].z;
            s += lrelu((float)e[3] + xrv[c].w) * attv[c].w;
        }
        logits[(long)p * 2 + hh] = s;
    }
}

__global__ __launch_bounds__(256)
void gat_mden_kernel(const float* __restrict__ logits, const float* __restrict__ self_logits,
                     const int* __restrict__ rowptr, float* __restrict__ m_arr,
                     float* __restrict__ den_arr, int n) {
    int t = blockIdx.x * blockDim.x + threadIdx.x;
    int i = t >> 1, hh = t & 1;
    if (i >= n) return;
    int p0 = rowptr[i], p1 = rowptr[i + 1];
    float m = self_logits[i * 2 + hh];
    for (int p = p0; p < p1; ++p) m = fmaxf(m, logits[(long)p * 2 + hh]);
    float den = expf(self_logits[i * 2 + hh] - m);
    for (int p = p0; p < p1; ++p) den += expf(logits[(long)p * 2 + hh] - m);
    m_arr[i * 2 + hh] = m;
    den_arr[i * 2 + hh] = den;
}

__global__ __launch_bounds__(256)
void gat_out_kernel(const _Float16* __restrict__ xl, const int* __restrict__ rowptr,
                    const int* __restrict__ csr_src, const float* __restrict__ logits,
                    const float* __restrict__ self_logits, const float* __restrict__ m_arr,
                    const float* __restrict__ den_arr, const float* __restrict__ bias,
                    _Float16* __restrict__ Fout, int n) {
    int i = (blockIdx.x * blockDim.x + threadIdx.x) >> 6;
    int lane = threadIdx.x & 63;
    if (i >= n) return;
    int hh = lane >> 5;
    float m = m_arr[i * 2 + hh];
    float inv = 1.f / (den_arr[i * 2 + hh] + 1e-16f);
    float acc = expf(self_logits[i * 2 + hh] - m) * inv * (float)xl[(size_t)i * SHS + lane];
    int p0 = rowptr[i], p1 = rowptr[i + 1];
    for (int p = p0; p < p1; ++p) {
        float w = expf(logits[(long)p * 2 + hh] - m) * inv;
        acc += w * (float)xl[(size_t)csr_src[p] * SHS + lane];
    }
    float r = fmaxf(acc + bias[lane], 0.f);   // bias + ReLU fused
    Fout[(size_t)i * SHS + lane] = (_Float16)r;
}

__global__ void sigmoid_kernel(const float* __restrict__ in, float* __restrict__ out, int n4) {
    int i = blockIdx.x * blockDim.x + threadIdx.x;
    if (i < n4) {
        float4 v = ((const float4*)in)[i];
        float4 r;
        r.x = 1.f / (1.f + expf(-v.x));
        r.y = 1.f / (1.f + expf(-v.y));
        r.z = 1.f / (1.f + expf(-v.z));
        r.w = 1.f / (1.f + expf(-v.w));
        ((float4*)out)[i] = r;
    }
}

// ---------------- launch ----------------
extern "C" void kernel_launch(void* const* d_in, const int* in_sizes, int n_in,
                              void* d_out, int out_size, void* d_ws, size_t ws_size,
                              hipStream_t stream) {
    const int N = NN;
    const int E = in_sizes[1] / 2;

    struct WSpec { int idx; int K, M; };
    const WSpec wspec[11] = {
        {2, 300, 256},   // W1
        {4, 256, 256},   // W2
        {5, 256, 128},   // W3
        {7, 128, 64},    // W4
        {9, 64, 32},     // W5
        {11, 32, 64},    // Wl
        {12, 32, 64},    // Wr
        {15, 64, 128},   // Wd1
        {17, 128, 256},  // Wd2
        {19, 256, 256},  // Wd3
        {20, 256, 300},  // Wd4
    };
    size_t arena_elems = 0;
    int kp[11], mp[11];
    size_t woff[11];
    for (int i = 0; i < 11; i++) {
        kp[i] = (wspec[i].K + 31) & ~31;
        mp[i] = (wspec[i].M + 63) & ~63;
        woff[i] = arena_elems;
        arena_elems += (size_t)2 * mp[i] * kp[i];  // hi + lo
    }

    size_t need = 0;
    need += (size_t)N * XS * 2;          // FX
    need += (size_t)N * SHS * 2 * 2;     // F0, F1
    need += (size_t)E * 4;               // csr_w
    need += (size_t)E * 2 * 4;           // logits
    need += (size_t)N * 2 * 4 * 3;       // self_logits, m_arr, den_arr
    need += (size_t)N * 4 * 3;           // dinv, deg, cursor
    need += (size_t)(N + 4) * 4;         // rowptr
    need += (size_t)E * 4;               // csr_src
    need += arena_elems * 2 + 128;       // f16 weight arena + align slack
    if (ws_size < need) return;

    const float* x      = (const float*)d_in[0];
    const int*   ei     = (const int*)d_in[1];
    const int*   e_src  = ei;
    const int*   e_dst  = ei + E;
    const float* b1  = (const float*)d_in[3];
    const float* b3  = (const float*)d_in[6];
    const float* b4  = (const float*)d_in[8];
    const float* b5  = (const float*)d_in[10];
    const float* attw= (const float*)d_in[13];
    const float* bg  = (const float*)d_in[14];
    const float* bd1 = (const float*)d_in[16];
    const float* bd2 = (const float*)d_in[18];
    const float* bd4 = (const float*)d_in[21];

    char* w = (char*)d_ws;
    _Float16* FX = (_Float16*)w;             w += (size_t)N * XS * 2;
    _Float16* F0 = (_Float16*)w;             w += (size_t)N * SHS * 2;
    _Float16* F1 = (_Float16*)w;             w += (size_t)N * SHS * 2;
    float* csr_w = (float*)w;                w += (size_t)E * 4;
    float* logits = (float*)w;               w += (size_t)E * 2 * 4;
    float* self_logits = (float*)w;          w += (size_t)N * 2 * 4;
    float* m_arr = (float*)w;                w += (size_t)N * 2 * 4;
    float* den_arr = (float*)w;              w += (size_t)N * 2 * 4;
    float* dinv = (float*)w;                 w += (size_t)N * 4;
    int* deg = (int*)w;                      w += (size_t)N * 4;
    int* rowptr = (int*)w;                   w += (size_t)(N + 4) * 4;
    int* cursor = (int*)w;                   w += (size_t)N * 4;
    int* csr_src = (int*)w;                  w += (size_t)E * 4;
    w = (char*)(((size_t)w + 63) & ~(size_t)63);
    _Float16* arena = (_Float16*)w;          w += arena_elems * 2;
    float* T = (float*)d_out;                // fp32 tmp (xr [N][64]; final [N][300])

    int nb_e = (E + 255) / 256;
    int nb_n = (N + 255) / 256;
    int nb_wave = (N + 3) / 4;
    int nb_2n = (2 * N + 255) / 256;

    // weight split + input convert
    for (int i = 0; i < 11; i++) {
        int total = mp[i] * kp[i];
        splitw_kernel<<<(total + 255) / 256, 256, 0, stream>>>(
            (const float*)d_in[wspec[i].idx], arena + woff[i], arena + woff[i] + total,
            wspec[i].K, wspec[i].M, kp[i], total);
    }
    cvt_x_kernel<<<((N * XS) + 255) / 256, 256, 0, stream>>>(x, FX, N * XS);

    // CSR build
    hipMemsetAsync(deg, 0, (size_t)N * 4, stream);
    hist_kernel<<<nb_e, 256, 0, stream>>>(e_dst, deg, E);
    scan_kernel<<<1, 1024, 0, stream>>>(deg, rowptr, N);
    dinv_kernel<<<nb_n, 256, 0, stream>>>(deg, dinv, N);
    copy_int_kernel<<<nb_n, 256, 0, stream>>>(rowptr, cursor, N);
    fill_kernel<<<nb_e, 256, 0, stream>>>(e_src, e_dst, dinv, cursor, csr_src, csr_w, E);

    auto gemm = [&](int wi, const _Float16* A, int lda, float* Cf, _Float16* Co,
                    float cAB, float cA, const float* bias) {
        int M = wspec[wi].M;
        int Kl = kp[wi];
        int total = mp[wi] * kp[wi];
        int gx = (M + 63) / 64, gy = (N + 63) / 64;
        gemm_f16_kernel<<<gx * gy, 256, 0, stream>>>(
            A, lda, arena + woff[wi], arena + woff[wi] + total,
            Cf, Co, N, Kl, M, cAB, cA, bias, gx);
    };
    auto prop = [&](const _Float16* Fin, _Float16* Fout, int D, float cP, float cH,
                    const float* bias) {
        int npw = 64 / (D >> 2);
        int npb = 4 * npw;
        int nb = (N + npb - 1) / npb;
        prop_kernel<<<nb, 256, 0, stream>>>(Fin, Fout, rowptr, csr_src, csr_w, dinv,
                                            bias, N, D, cP, cH);
    };

    // 1. gemm0: FX @ W1 -> F0 [256]
    gemm(0, FX, XS, nullptr, F0, 1.f, 0.f, nullptr);
    // 2. prop L1: F0 -> F1 (bias b1)
    prop(F0, F1, 256, 1.f, 0.f, b1);
    // 3. prop L2 (GCN2 hp): F1 -> F0
    prop(F1, F0, 256, 1.f - ALPHA_C, ALPHA_C, nullptr);
    // 4. gemm1: F0 -> F1  (beta*hp@W2 + (1-beta)*hp)
    gemm(1, F0, SHS, nullptr, F1, BETA_C, 1.f - BETA_C, nullptr);
    // 5. gemm2: F1 -> F0 [128]
    gemm(2, F1, SHS, nullptr, F0, 1.f, 0.f, nullptr);
    // 6. prop L3: F0 -> F1 (b3)
    prop(F0, F1, 128, 1.f, 0.f, b3);
    // 7. gemm3: F1 -> F0 [64]
    gemm(3, F1, SHS, nullptr, F0, 1.f, 0.f, nullptr);
    // 8. prop L4: F0 -> F1 (b4)
    prop(F0, F1, 64, 1.f, 0.f, b4);
    // 9. gemm4: F1 -> F0 [32]
    gemm(4, F1, SHS, nullptr, F0, 1.f, 0.f, nullptr);
    // 10. prop L5: F0 -> F1 (b5)
    prop(F0, F1, 32, 1.f, 0.f, b5);
    // 11. gemm5 (xl): F1 -> F0 [64]
    gemm(5, F1, SHS, nullptr, F0, 1.f, 0.f, nullptr);
    // 12. gemm6 (xr): F1 -> T fp32 [N][64]
    gemm(6, F1, SHS, T, nullptr, 1.f, 0.f, nullptr);
    // 13-15. GAT: xl=F0, xr=T -> F1 (ReLU+bg)
    gat_logits_kernel<<<nb_2n, 256, 0, stream>>>(F0, T, attw, rowptr, csr_src,
                                                 logits, self_logits, N);
    gat_mden_kernel<<<nb_2n, 256, 0, stream>>>(logits, self_logits, rowptr, m_arr, den_arr, N);
    gat_out_kernel<<<nb_wave, 256, 0, stream>>>(F0, rowptr, csr_src, logits, self_logits,
                                                m_arr, den_arr, bg, F1, N);
    // 16. prop dec1: F1 -> F0 [64]
    prop(F1, F0, 64, 1.f, 0.f, nullptr);
    // 17. gemm7: F0 -> F1 [128] (bd1)
    gemm(7, F0, SHS, nullptr, F1, 1.f, 0.f, bd1);
    // 18. prop dec2: F1 -> F0 [128]
    prop(F1, F0, 128, 1.f, 0.f, nullptr);
    // 19. gemm8: F0 -> F1 [256] (bd2)
    gemm(8, F0, SHS, nullptr, F1, 1.f, 0.f, bd2);
    // 20. prop dec3 (GCN2 hp): F1 -> F0
    prop(F1, F0, 256, 1.f - ALPHA_C, ALPHA_C, nullptr);
    // 21. gemm9: F0 -> F1
    gemm(9, F0, SHS, nullptr, F1, BETA_C, 1.f - BETA_C, nullptr);
    // 22. prop dec4: F1 -> F0
    prop(F1, F0, 256, 1.f, 0.f, nullptr);
    // 23. gemm10: F0 -> T fp32 [300] (bd4)
    gemm(10, F0, SHS, T, nullptr, 1.f, 0.f, bd4);
    // 24. sigmoid in-place on d_out
    sigmoid_kernel<<<(out_size / 4 + 255) / 256, 256, 0, stream>>>(T, (float*)d_out, out_size / 4);
}